// Round 8
// baseline (1448.386 us; speedup 1.0000x reference)
//
#include <hip/hip_runtime.h>

// convEP: 10-step EP relaxation, MFMA fp16 2-way-split convs (fp32-equivalent).
//   s0' = rho(fc(s1));  s1' = rho(pool(conv0(s2)) + fc^T(s0));  s2' = rho(p2 + convT(unpool(s1, idx1)))
// fp32 x = xh + 2^-12*xl' (fp16 planes, lo pre-scaled 2^12 to stay fp16-normal).
// x*y ~= xh*yh + 2^-12*(xh*yl' + xl'*yh); acc_hi/acc_lo separate, combined at epilogue.
// MFMA 16x16x32_f16: A[m=l16][k=quad*8+j], B[k=quad*8+j][n=l16], C/D: col=l16, row=quad*4+reg.
// R8: fix R7's missing b*32768 in k_convT's u staging (each block read image 0's u).

typedef _Float16 half8 __attribute__((ext_vector_type(8)));
typedef float f32x4 __attribute__((ext_vector_type(4)));
#define MFMA_F16(A, B, C) __builtin_amdgcn_mfma_f32_16x16x32_f16((A), (B), (C), 0, 0, 0)
#define LO_SCALE 2.44140625e-4f   // 2^-12

static __device__ __forceinline__ float rho_(float x) {
  return fminf(fmaxf(x, 0.0f), 1.0f);
}
// split v = h + lo/4096 (lo prescaled so both planes stay fp16-normal)
static __device__ __forceinline__ void split2(float v, _Float16& h, _Float16& l) {
  if (fabsf(v) < 6.1035156e-5f) {
    h = (_Float16)0.f;
    l = (_Float16)(v * 4096.f);
  } else {
    h = (_Float16)v;
    l = (_Float16)((v - (float)h) * 4096.f);
  }
}

// ---------------- K0: one-time weight split+transpose (fp16 hi/lo-scaled planes) ----------------
// wA0[((tap*2+ck)*128 + co)*32 + cik] = conv0w[co][ck*32+cik][tap]   (conv0 A: m=co, k=ci)
// wA1[((tap*4+c )*64  + o )*32 + cpk] = conv0w[(c*32+cpk)][o][tap]   (convT A: m=o,  k=cp)
__global__ __launch_bounds__(256) void k_wprep(
    const float* __restrict__ w0,
    _Float16* __restrict__ wA0h, _Float16* __restrict__ wA0l,
    _Float16* __restrict__ wA1h, _Float16* __restrict__ wA1l) {
  int i = blockIdx.x * 256 + threadIdx.x;
  if (i >= 204800) return;
  {
    int cik = i & 31, t1 = i >> 5;
    int co = t1 & 127, t2 = t1 >> 7;
    int ck = t2 & 1, tap = t2 >> 1;
    float v = w0[(co * 64 + ck * 32 + cik) * 25 + tap];
    _Float16 h, l; split2(v, h, l);
    wA0h[i] = h; wA0l[i] = l;
  }
  {
    int cpk = i & 31, t1 = i >> 5;
    int o = t1 & 63, t2 = t1 >> 6;
    int c = t2 & 3, tap = t2 >> 2;
    float v = w0[((c * 32 + cpk) * 64 + o) * 25 + tap];
    _Float16 h, l; split2(v, h, l);
    wA1h[i] = h; wA1l[i] = l;
  }
}

// ---------------- K1: p2 = maxpool2x2(conv2d(data, conv1_w) + conv1_b) (once, fp32) ----------------
__global__ __launch_bounds__(256) void k_p2(
    const float* __restrict__ data, const float* __restrict__ w,
    const float* __restrict__ bias, float* __restrict__ p2) {
  __shared__ float ld[3][36][36];
  __shared__ float lw[80];
  int b = blockIdx.x, co = blockIdx.y, tid = threadIdx.x;
  for (int i = tid; i < 3 * 36 * 36; i += 256) {
    int ci = i / 1296, rem = i % 1296, y = rem / 36, x = rem % 36;
    int gy = y - 2, gx = x - 2;
    float v = 0.f;
    if (gy >= 0 && gy < 32 && gx >= 0 && gx < 32)
      v = data[(b * 3 + ci) * 1024 + gy * 32 + gx];
    ld[ci][y][x] = v;
  }
  if (tid < 75) lw[tid] = w[co * 75 + tid];
  __syncthreads();
  int ph = tid >> 4, pw = tid & 15;
  float bv = bias[co];
  float a00 = bv, a01 = bv, a10 = bv, a11 = bv;
  int ry = 2 * ph, rx = 2 * pw;
  for (int ci = 0; ci < 3; ci++) {
#pragma unroll
    for (int ky = 0; ky < 5; ky++) {
#pragma unroll
      for (int kx = 0; kx < 5; kx++) {
        float wv = lw[(ci * 5 + ky) * 5 + kx];
        a00 += wv * ld[ci][ry + ky][rx + kx];
        a01 += wv * ld[ci][ry + ky][rx + kx + 1];
        a10 += wv * ld[ci][ry + ky + 1][rx + kx];
        a11 += wv * ld[ci][ry + ky + 1][rx + kx + 1];
      }
    }
  }
  float m = fmaxf(fmaxf(a00, a01), fmaxf(a10, a11));
  p2[((b * 64 + co) * 16 + ph) * 16 + pw] = m;
}

// ---------------- K2: MFMA conv0 + pool/argmax + fused s1 update; writes s1_new, uh/ul ----------------
// grid (64 b, 4 quad, 2 cg) = 512 blocks, 256 thr = 4 waves. Wave = n-tile nt (2 rows of quad),
// m = 4 tiles (this cg's 64 co), K = 64 ci (2 kc). u written split as fp16 [b][pos 256][cp 128].
__global__ __launch_bounds__(256, 2) void k_conv0(
    const float* __restrict__ s2,
    const _Float16* __restrict__ wA0h, const _Float16* __restrict__ wA0l,
    const float* __restrict__ b0, const float* __restrict__ s1old,
    const float* __restrict__ s0old, const float* __restrict__ fcw,
    float* __restrict__ s1new, _Float16* __restrict__ uh, _Float16* __restrict__ ul) {
  __shared__ __align__(16) _Float16 sm[2 * 10368];  // [plane][pos 144][ci 64+8pad] = 41472 B
  int b = blockIdx.x, q = blockIdx.y, cg = blockIdx.z, tid = threadIdx.x;
  int qy = q >> 1, qx = q & 1;

  const float* s2b = s2 + b * 16384;
  for (int i = tid; i < 9216; i += 256) {
    int ci = i / 144, pos = i % 144;
    int ty = pos / 12, tx = pos % 12;
    int gy = qy * 8 - 2 + ty, gx = qx * 8 - 2 + tx;
    float v = 0.f;
    if (gy >= 0 && gy < 16 && gx >= 0 && gx < 16) v = s2b[ci * 256 + gy * 16 + gx];
    _Float16 h, l; split2(v, h, l);
    sm[pos * 72 + ci] = h;
    sm[10368 + pos * 72 + ci] = l;
  }
  __syncthreads();

  int lane = tid & 63, nt = tid >> 6;
  int l16 = lane & 15, quad = lane >> 4;
  int wy = (l16 >> 1) & 1;
  int x_l = ((l16 >> 2) << 1) + (l16 & 1);

  f32x4 acch[4], accl[4];
#pragma unroll
  for (int mt = 0; mt < 4; mt++) {
    int cb = cg * 64 + mt * 16 + quad * 4;
    f32x4 bi; bi[0] = b0[cb]; bi[1] = b0[cb + 1]; bi[2] = b0[cb + 2]; bi[3] = b0[cb + 3];
    f32x4 z; z[0] = 0.f; z[1] = 0.f; z[2] = 0.f; z[3] = 0.f;
    acch[mt] = bi; accl[mt] = z;
  }

  for (int tap = 0; tap < 25; tap++) {
    int ky = tap / 5, kx = tap % 5;
    int pos = (2 * nt + wy + ky) * 12 + x_l + kx;
#pragma unroll
    for (int kc = 0; kc < 2; kc++) {
      const _Float16* ap  = wA0h + ((tap * 2 + kc) * 128 + cg * 64 + l16) * 32 + quad * 8;
      const _Float16* alp = wA0l + ((tap * 2 + kc) * 128 + cg * 64 + l16) * 32 + quad * 8;
      half8 ah[4], al[4];
#pragma unroll
      for (int mt = 0; mt < 4; mt++) {
        ah[mt] = *(const half8*)(ap + mt * 512);
        al[mt] = *(const half8*)(alp + mt * 512);
      }
      half8 bh = *(const half8*)(sm + pos * 72 + kc * 32 + quad * 8);
      half8 bl = *(const half8*)(sm + 10368 + pos * 72 + kc * 32 + quad * 8);
#pragma unroll
      for (int mt = 0; mt < 4; mt++) {
        acch[mt] = MFMA_F16(ah[mt], bh, acch[mt]);
        accl[mt] = MFMA_F16(al[mt], bh, accl[mt]);
        accl[mt] = MFMA_F16(ah[mt], bl, accl[mt]);
      }
    }
  }

  // C -> LDS (reuse), Cb[co 64][66]
  __syncthreads();
  float* Cb = (float*)sm;   // 64*66*4 = 16896 B
  int p64 = (2 * nt + wy) * 8 + x_l;
#pragma unroll
  for (int mt = 0; mt < 4; mt++) {
#pragma unroll
    for (int r = 0; r < 4; r++) {
      Cb[(mt * 16 + quad * 4 + r) * 66 + p64] = acch[mt][r] + LO_SCALE * accl[mt][r];
    }
  }
  __syncthreads();

  // pool/argmax + fused s1 update + u scatter (split fp16 planes)
  for (int it = 0; it < 4; it++) {
    int idx = it * 256 + tid;          // 1024 = 64 co x 16 windows
    int co = idx >> 4, win = idx & 15;
    int wy2 = win >> 2, wx2 = win & 3;
    int base = co * 66 + wy2 * 16 + wx2 * 2;
    float v0 = Cb[base], v1 = Cb[base + 1], v2 = Cb[base + 8], v3 = Cb[base + 9];
    float m0 = v0; int id = 0;
    if (v1 > m0) { m0 = v1; id = 1; }
    if (v2 > m0) { m0 = v2; id = 2; }
    if (v3 > m0) { m0 = v3; id = 3; }
    int co_g = cg * 64 + co;
    int ph = qy * 4 + wy2, pw = qx * 4 + wx2;
    int j = co_g * 64 + ph * 8 + pw;
    float a = m0;
#pragma unroll
    for (int k = 0; k < 10; k++) a += s0old[b * 10 + k] * fcw[k * 8192 + j];
    s1new[b * 8192 + j] = rho_(a);
    float sv = s1old[b * 8192 + j];
    _Float16 hh, hl; split2(sv, hh, hl);
    int gp = (qy * 8 + wy2 * 2) * 16 + (qx * 8 + wx2 * 2);
    int bu = (b * 256 + gp) * 128 + co_g;
    uh[bu]        = (id == 0) ? hh : (_Float16)0.f;
    ul[bu]        = (id == 0) ? hl : (_Float16)0.f;
    uh[bu + 128]  = (id == 1) ? hh : (_Float16)0.f;
    ul[bu + 128]  = (id == 1) ? hl : (_Float16)0.f;
    uh[bu + 2048] = (id == 2) ? hh : (_Float16)0.f;
    ul[bu + 2048] = (id == 2) ? hl : (_Float16)0.f;
    uh[bu + 2176] = (id == 3) ? hh : (_Float16)0.f;
    ul[bu + 2176] = (id == 3) ? hl : (_Float16)0.f;
  }
}

// ---------------- K3: MFMA convT partial (K-split) ----------------
// up[o,y,x] = sum_{cp,ky,kx} W0[cp][o][ky][kx] * u[cp, y+2-ky, x+2-kx]
// grid (64 b, 4 quad, 2 ks) = 512 blocks, 4 waves = n-tiles. Wave: m = 4 tiles (64 o),
// K = this block's 64 cp (2 kc). Single pass (both u planes resident in LDS).
__global__ __launch_bounds__(256, 2) void k_convT(
    const _Float16* __restrict__ uh, const _Float16* __restrict__ ul,
    const _Float16* __restrict__ wA1h, const _Float16* __restrict__ wA1l,
    float* __restrict__ upPart) {
  __shared__ __align__(16) _Float16 sm[2 * 10368];  // [plane][pos 144][cp 64+8pad]
  int b = blockIdx.x, q = blockIdx.y, ks = blockIdx.z, tid = threadIdx.x;
  int qy = q >> 1, qx = q & 1;

  // stage u planes (uint = 2 halves per load, coalesced). NOTE b*32768 (R7 bug fix).
  for (int i = tid; i < 4608; i += 256) {
    int pos = i >> 5, u2 = i & 31;       // u2: pair-of-cp index
    int ty = pos / 12, tx = pos % 12;
    int gy = qy * 8 - 2 + ty, gx = qx * 8 - 2 + tx;
    unsigned vh = 0, vl = 0;
    if (gy >= 0 && gy < 16 && gx >= 0 && gx < 16) {
      int off = b * 32768 + (gy * 16 + gx) * 128 + ks * 64 + u2 * 2;
      vh = *(const unsigned*)(uh + off);
      vl = *(const unsigned*)(ul + off);
    }
    *(unsigned*)(sm + pos * 72 + u2 * 2) = vh;
    *(unsigned*)(sm + 10368 + pos * 72 + u2 * 2) = vl;
  }
  __syncthreads();

  int lane = tid & 63, nt = tid >> 6;
  int l16 = lane & 15, quad = lane >> 4;
  int wy = (l16 >> 1) & 1;
  int x_l = ((l16 >> 2) << 1) + (l16 & 1);

  f32x4 acch[4], accl[4];
#pragma unroll
  for (int mt = 0; mt < 4; mt++) {
    f32x4 z; z[0] = 0.f; z[1] = 0.f; z[2] = 0.f; z[3] = 0.f;
    acch[mt] = z; accl[mt] = z;
  }

  for (int tap = 0; tap < 25; tap++) {
    int ky = tap / 5, kx = tap % 5;
    int pos = (2 * nt + wy + 4 - ky) * 12 + x_l + 4 - kx;
#pragma unroll
    for (int kc = 0; kc < 2; kc++) {
      int c = ks * 2 + kc;
      const _Float16* ap  = wA1h + ((tap * 4 + c) * 64 + l16) * 32 + quad * 8;
      const _Float16* alp = wA1l + ((tap * 4 + c) * 64 + l16) * 32 + quad * 8;
      half8 ah[4], al[4];
#pragma unroll
      for (int mt = 0; mt < 4; mt++) {
        ah[mt] = *(const half8*)(ap + mt * 512);
        al[mt] = *(const half8*)(alp + mt * 512);
      }
      half8 bh = *(const half8*)(sm + pos * 72 + kc * 32 + quad * 8);
      half8 bl = *(const half8*)(sm + 10368 + pos * 72 + kc * 32 + quad * 8);
#pragma unroll
      for (int mt = 0; mt < 4; mt++) {
        acch[mt] = MFMA_F16(ah[mt], bh, acch[mt]);
        accl[mt] = MFMA_F16(al[mt], bh, accl[mt]);
        accl[mt] = MFMA_F16(ah[mt], bl, accl[mt]);
      }
    }
  }

  // direct partial store: wave owns rows (2nt+wy), cols x_l of quadrant; o from (mt,quad,r)
  int y = qy * 8 + 2 * nt + wy, x = qx * 8 + x_l;
  float* op = upPart + ks * 1048576 + b * 16384;
#pragma unroll
  for (int mt = 0; mt < 4; mt++) {
#pragma unroll
    for (int r = 0; r < 4; r++) {
      int o = mt * 16 + quad * 4 + r;
      op[o * 256 + y * 16 + x] = acch[mt][r] + LO_SCALE * accl[mt][r];
    }
  }
}

// ---------------- K3b: s2_new = rho(p2 + up0 + up1) ----------------
__global__ __launch_bounds__(256) void k_s2comb(
    const float* __restrict__ p2, const float* __restrict__ a,
    const float* __restrict__ b, float* __restrict__ s2new) {
  int i = blockIdx.x * 256 + threadIdx.x;   // over 262144 float4s
  float4 p = ((const float4*)p2)[i];
  float4 av = ((const float4*)a)[i];
  float4 bv = ((const float4*)b)[i];
  float4 o;
  o.x = rho_(p.x + av.x + bv.x);
  o.y = rho_(p.y + av.y + bv.y);
  o.z = rho_(p.z + av.z + bv.z);
  o.w = rho_(p.w + av.w + bv.w);
  ((float4*)s2new)[i] = o;
}

// ---------------- K5: s0_new = rho(s1_old_flat @ fc_w^T + fc_b) ----------------
__global__ __launch_bounds__(256) void k_s0fc(
    const float* __restrict__ s1old, const float* __restrict__ fcw,
    const float* __restrict__ fcb, float* __restrict__ s0new) {
  __shared__ float red[10][256];
  int b = blockIdx.x, tid = threadIdx.x;
  float acc[10];
#pragma unroll
  for (int o = 0; o < 10; o++) acc[o] = 0.f;
  const float* sb = s1old + b * 8192;
  for (int i = tid; i < 8192; i += 256) {
    float v = sb[i];
#pragma unroll
    for (int o = 0; o < 10; o++) acc[o] += v * fcw[o * 8192 + i];
  }
#pragma unroll
  for (int o = 0; o < 10; o++) red[o][tid] = acc[o];
  __syncthreads();
  for (int s = 128; s > 0; s >>= 1) {
    if (tid < s) {
#pragma unroll
      for (int o = 0; o < 10; o++) red[o][tid] += red[o][tid + s];
    }
    __syncthreads();
  }
  if (tid < 10) s0new[b * 10 + tid] = rho_(red[tid][0] + fcb[tid]);
}

extern "C" void kernel_launch(void* const* d_in, const int* in_sizes, int n_in,
                              void* d_out, int out_size, void* d_ws, size_t ws_size,
                              hipStream_t stream) {
  const float* data   = (const float*)d_in[0];
  const float* s0init = (const float*)d_in[1];   // zeros
  const float* s1init = (const float*)d_in[2];   // zeros
  const float* s2init = (const float*)d_in[3];   // zeros
  const float* conv0w = (const float*)d_in[4];
  const float* conv0b = (const float*)d_in[5];
  const float* conv1w = (const float*)d_in[6];
  const float* conv1b = (const float*)d_in[7];
  const float* fcw    = (const float*)d_in[8];
  const float* fcb    = (const float*)d_in[9];

  // workspace layout (~30 MB)
  float* p = (float*)d_ws;
  float* s0buf[2] = {p, p + 640};            p += 1280;
  float* s1buf[2] = {p, p + 524288};         p += 1048576;
  float* s2buf[2] = {p, p + 1048576};        p += 2097152;
  float* p2 = p;                             p += 1048576;
  float* upPart = p;                         p += 2097152;   // 2 x 1M floats
  _Float16* hq = (_Float16*)p;
  _Float16* uh   = hq;                       hq += 2097152;  // [b][pos 256][cp 128]
  _Float16* ul   = hq;                       hq += 2097152;
  _Float16* wA0h = hq;                       hq += 204800;
  _Float16* wA0l = hq;                       hq += 204800;
  _Float16* wA1h = hq;                       hq += 204800;
  _Float16* wA1l = hq;                       hq += 204800;

  k_wprep<<<800, 256, 0, stream>>>(conv0w, wA0h, wA0l, wA1h, wA1l);
  k_p2<<<dim3(64, 64), 256, 0, stream>>>(data, conv1w, conv1b, p2);

  const float* s0o = s0init;
  const float* s1o = s1init;
  const float* s2o = s2init;
  float* outp = (float*)d_out;

  for (int t = 0; t < 10; t++) {
    int nb = t & 1;
    float* s0w = s0buf[nb];
    float* s1w = s1buf[nb];
    float* s2w = s2buf[nb];

    // conv0(s2_old) + pool/argmax; s1_new = rho(p1 + fc^T(s0_old)); u = split(unpool(s1_old, idx))
    k_conv0<<<dim3(64, 4, 2), 256, 0, stream>>>(s2o, wA0h, wA0l, conv0b, s1o, s0o, fcw, s1w, uh, ul);
    // s0_new = rho(fc(s1_old))
    k_s0fc<<<64, 256, 0, stream>>>(s1o, fcw, fcb, s0w);
    // convT partials + combine: s2_new = rho(p2 + up0 + up1)
    k_convT<<<dim3(64, 4, 2), 256, 0, stream>>>(uh, ul, wA1h, wA1l, upPart);
    k_s2comb<<<1024, 256, 0, stream>>>(p2, upPart, upPart + 1048576, s2w);

    s0o = s0w; s1o = s1w; s2o = s2w;

    if (t == 6) {   // PRED_T snapshot (post-update states)
      hipMemcpyAsync(outp + 1573504, s0w, 640 * sizeof(float),     hipMemcpyDeviceToDevice, stream);
      hipMemcpyAsync(outp + 1574144, s1w, 524288 * sizeof(float),  hipMemcpyDeviceToDevice, stream);
      hipMemcpyAsync(outp + 2098432, s2w, 1048576 * sizeof(float), hipMemcpyDeviceToDevice, stream);
    }
  }

  // final states
  hipMemcpyAsync(outp + 0,      s0o, 640 * sizeof(float),     hipMemcpyDeviceToDevice, stream);
  hipMemcpyAsync(outp + 640,    s1o, 524288 * sizeof(float),  hipMemcpyDeviceToDevice, stream);
  hipMemcpyAsync(outp + 524928, s2o, 1048576 * sizeof(float), hipMemcpyDeviceToDevice, stream);
}

// Round 9
// 1169.365 us; speedup vs baseline: 1.2386x; 1.2386x over previous
//
#include <hip/hip_runtime.h>

// convEP: 10-step EP relaxation, MFMA fp16 2-way-split convs (fp32-equivalent).
//   s0' = rho(fc(s1));  s1' = rho(pool(conv0(s2)) + fc^T(s0));  s2' = rho(p2 + convT(unpool(s1, idx1)))
// fp32 x = xh + 2^-12*xl' (fp16 planes, lo pre-scaled 2^12 to stay fp16-normal).
// x*y ~= xh*yh + 2^-12*(xh*yl' + xl'*yh); acc_hi/acc_lo separate, combined at epilogue.
// MFMA 16x16x32_f16: A[m=l16][k=quad*8+j], B[k=quad*8+j][n=l16], C/D: col=l16, row=quad*4+reg.
// R9: A-register-reuse — block = 128 thr = 2 waves (K-split kc), wave loops nt=4 n-tiles
// (whole quadrant) with A-frags resident in regs (A-rate /4). K-partials combined via LDS.

typedef _Float16 half8 __attribute__((ext_vector_type(8)));
typedef float f32x4 __attribute__((ext_vector_type(4)));
#define MFMA_F16(A, B, C) __builtin_amdgcn_mfma_f32_16x16x32_f16((A), (B), (C), 0, 0, 0)
#define LO_SCALE 2.44140625e-4f   // 2^-12

static __device__ __forceinline__ float rho_(float x) {
  return fminf(fmaxf(x, 0.0f), 1.0f);
}
// split v = h + lo/4096 (lo prescaled so both planes stay fp16-normal)
static __device__ __forceinline__ void split2(float v, _Float16& h, _Float16& l) {
  if (fabsf(v) < 6.1035156e-5f) {
    h = (_Float16)0.f;
    l = (_Float16)(v * 4096.f);
  } else {
    h = (_Float16)v;
    l = (_Float16)((v - (float)h) * 4096.f);
  }
}

// ---------------- K0: one-time weight split+transpose (fp16 hi/lo-scaled planes) ----------------
// wA0[((tap*2+ck)*128 + co)*32 + cik] = conv0w[co][ck*32+cik][tap]   (conv0 A: m=co, k=ci)
// wA1[((tap*4+c )*64  + o )*32 + cpk] = conv0w[(c*32+cpk)][o][tap]   (convT A: m=o,  k=cp)
__global__ __launch_bounds__(256) void k_wprep(
    const float* __restrict__ w0,
    _Float16* __restrict__ wA0h, _Float16* __restrict__ wA0l,
    _Float16* __restrict__ wA1h, _Float16* __restrict__ wA1l) {
  int i = blockIdx.x * 256 + threadIdx.x;
  if (i >= 204800) return;
  {
    int cik = i & 31, t1 = i >> 5;
    int co = t1 & 127, t2 = t1 >> 7;
    int ck = t2 & 1, tap = t2 >> 1;
    float v = w0[(co * 64 + ck * 32 + cik) * 25 + tap];
    _Float16 h, l; split2(v, h, l);
    wA0h[i] = h; wA0l[i] = l;
  }
  {
    int cpk = i & 31, t1 = i >> 5;
    int o = t1 & 63, t2 = t1 >> 6;
    int c = t2 & 3, tap = t2 >> 2;
    float v = w0[((c * 32 + cpk) * 64 + o) * 25 + tap];
    _Float16 h, l; split2(v, h, l);
    wA1h[i] = h; wA1l[i] = l;
  }
}

// ---------------- K1: p2 = maxpool2x2(conv2d(data, conv1_w) + conv1_b) (once, fp32) ----------------
// grid (64 b, 4 cg-of-16co), block 256 = 16x16 pooled positions; image staged once per block.
__global__ __launch_bounds__(256) void k_p2(
    const float* __restrict__ data, const float* __restrict__ w,
    const float* __restrict__ bias, float* __restrict__ p2) {
  __shared__ float ld[3][36][36];
  __shared__ float lw[16][80];
  __shared__ float lb[16];
  int b = blockIdx.x, cg = blockIdx.y, tid = threadIdx.x;
  for (int i = tid; i < 3 * 36 * 36; i += 256) {
    int ci = i / 1296, rem = i % 1296, y = rem / 36, x = rem % 36;
    int gy = y - 2, gx = x - 2;
    float v = 0.f;
    if (gy >= 0 && gy < 32 && gx >= 0 && gx < 32)
      v = data[(b * 3 + ci) * 1024 + gy * 32 + gx];
    ld[ci][y][x] = v;
  }
  for (int i = tid; i < 16 * 75; i += 256) {
    int co = i / 75, k = i % 75;
    lw[co][k] = w[(cg * 16 + co) * 75 + k];
  }
  if (tid < 16) lb[tid] = bias[cg * 16 + tid];
  __syncthreads();
  int ph = tid >> 4, pw = tid & 15;
  int ry = 2 * ph, rx = 2 * pw;
  for (int co = 0; co < 16; co++) {
    float bv = lb[co];
    float a00 = bv, a01 = bv, a10 = bv, a11 = bv;
    for (int ci = 0; ci < 3; ci++) {
#pragma unroll
      for (int ky = 0; ky < 5; ky++) {
#pragma unroll
        for (int kx = 0; kx < 5; kx++) {
          float wv = lw[co][(ci * 5 + ky) * 5 + kx];
          a00 += wv * ld[ci][ry + ky][rx + kx];
          a01 += wv * ld[ci][ry + ky][rx + kx + 1];
          a10 += wv * ld[ci][ry + ky + 1][rx + kx];
          a11 += wv * ld[ci][ry + ky + 1][rx + kx + 1];
        }
      }
    }
    float m = fmaxf(fmaxf(a00, a01), fmaxf(a10, a11));
    p2[((b * 64 + cg * 16 + co) * 16 + ph) * 16 + pw] = m;
  }
}

// ---------------- K2: MFMA conv0 + pool/argmax + fused s1 update; writes s1_new, uh/ul ----------------
// grid (64 b, 4 quad, 2 cg) = 512 blocks, 128 thr = 2 waves (kc 0/1). Wave: m = 4 mt
// (its cg's 64 co), K = 32 (its kc), n = 4 nt (all 64 quadrant pos). LDS C-combine.
__global__ __launch_bounds__(128, 2) void k_conv0(
    const float* __restrict__ s2,
    const _Float16* __restrict__ wA0h, const _Float16* __restrict__ wA0l,
    const float* __restrict__ b0, const float* __restrict__ s1old,
    const float* __restrict__ s0old, const float* __restrict__ fcw,
    float* __restrict__ s1new, _Float16* __restrict__ uh, _Float16* __restrict__ ul) {
  __shared__ __align__(16) _Float16 sm[2 * 10368];  // [plane][pos 144][ci 64+8pad] = 41472 B
  int b = blockIdx.x, q = blockIdx.y, cg = blockIdx.z, tid = threadIdx.x;
  int qy = q >> 1, qx = q & 1;

  const float* s2b = s2 + b * 16384;
  for (int i = tid; i < 9216; i += 128) {
    int ci = i / 144, pos = i % 144;
    int ty = pos / 12, tx = pos % 12;
    int gy = qy * 8 - 2 + ty, gx = qx * 8 - 2 + tx;
    float v = 0.f;
    if (gy >= 0 && gy < 16 && gx >= 0 && gx < 16) v = s2b[ci * 256 + gy * 16 + gx];
    _Float16 h, l; split2(v, h, l);
    sm[pos * 72 + ci] = h;
    sm[10368 + pos * 72 + ci] = l;
  }
  __syncthreads();

  int lane = tid & 63, kc = tid >> 6;
  int l16 = lane & 15, quad = lane >> 4;
  int wy = (l16 >> 1) & 1;
  int x_l = ((l16 >> 2) << 1) + (l16 & 1);

  f32x4 acch[4][4], accl[4][4];   // [nt][mt]
#pragma unroll
  for (int nt = 0; nt < 4; nt++)
#pragma unroll
    for (int mt = 0; mt < 4; mt++) {
      f32x4 z; z[0] = 0.f; z[1] = 0.f; z[2] = 0.f; z[3] = 0.f;
      accl[nt][mt] = z;
      if (kc == 0) {   // bias enters exactly once (kc=0 partial)
        int cb = cg * 64 + mt * 16 + quad * 4;
        f32x4 bi; bi[0] = b0[cb]; bi[1] = b0[cb + 1]; bi[2] = b0[cb + 2]; bi[3] = b0[cb + 3];
        acch[nt][mt] = bi;
      } else {
        acch[nt][mt] = z;
      }
    }

  for (int tap = 0; tap < 25; tap++) {
    int ky = tap / 5, kx = tap % 5;
    const _Float16* ap  = wA0h + ((tap * 2 + kc) * 128 + cg * 64 + l16) * 32 + quad * 8;
    const _Float16* alp = wA0l + ((tap * 2 + kc) * 128 + cg * 64 + l16) * 32 + quad * 8;
    half8 ah[4], al[4];
#pragma unroll
    for (int mt = 0; mt < 4; mt++) {
      ah[mt] = *(const half8*)(ap + mt * 512);
      al[mt] = *(const half8*)(alp + mt * 512);
    }
#pragma unroll
    for (int nt = 0; nt < 4; nt++) {
      int pos = (2 * nt + wy + ky) * 12 + x_l + kx;
      half8 bh = *(const half8*)(sm + pos * 72 + kc * 32 + quad * 8);
      half8 bl = *(const half8*)(sm + 10368 + pos * 72 + kc * 32 + quad * 8);
#pragma unroll
      for (int mt = 0; mt < 4; mt++) {
        acch[nt][mt] = MFMA_F16(ah[mt], bh, acch[nt][mt]);
        accl[nt][mt] = MFMA_F16(al[mt], bh, accl[nt][mt]);
        accl[nt][mt] = MFMA_F16(ah[mt], bl, accl[nt][mt]);
      }
    }
  }

  // combine planes, write this wave's K-partial to its LDS C-region [co 64][66]
  __syncthreads();
  float* Cb = (float*)sm;           // 2 regions x 4224 floats = 33792 B (fits in sm)
  float* myC = Cb + kc * 4224;
#pragma unroll
  for (int nt = 0; nt < 4; nt++) {
    int p64 = (2 * nt + wy) * 8 + x_l;
#pragma unroll
    for (int mt = 0; mt < 4; mt++) {
#pragma unroll
      for (int r = 0; r < 4; r++) {
        myC[(mt * 16 + quad * 4 + r) * 66 + p64] = acch[nt][mt][r] + LO_SCALE * accl[nt][mt][r];
      }
    }
  }
  __syncthreads();

  // pool/argmax + fused s1 update + u scatter (sum of both K-partials)
  for (int it = 0; it < 8; it++) {
    int idx = it * 128 + tid;          // 1024 = 64 co x 16 windows
    int co = idx >> 4, win = idx & 15;
    int wy2 = win >> 2, wx2 = win & 3;
    int base = co * 66 + wy2 * 16 + wx2 * 2;
    float v0 = Cb[base]     + Cb[4224 + base];
    float v1 = Cb[base + 1] + Cb[4224 + base + 1];
    float v2 = Cb[base + 8] + Cb[4224 + base + 8];
    float v3 = Cb[base + 9] + Cb[4224 + base + 9];
    float m0 = v0; int id = 0;
    if (v1 > m0) { m0 = v1; id = 1; }
    if (v2 > m0) { m0 = v2; id = 2; }
    if (v3 > m0) { m0 = v3; id = 3; }
    int co_g = cg * 64 + co;
    int ph = qy * 4 + wy2, pw = qx * 4 + wx2;
    int j = co_g * 64 + ph * 8 + pw;
    float a = m0;
#pragma unroll
    for (int k = 0; k < 10; k++) a += s0old[b * 10 + k] * fcw[k * 8192 + j];
    s1new[b * 8192 + j] = rho_(a);
    float sv = s1old[b * 8192 + j];
    _Float16 hh, hl; split2(sv, hh, hl);
    int gp = (qy * 8 + wy2 * 2) * 16 + (qx * 8 + wx2 * 2);
    int bu = (b * 256 + gp) * 128 + co_g;
    uh[bu]        = (id == 0) ? hh : (_Float16)0.f;
    ul[bu]        = (id == 0) ? hl : (_Float16)0.f;
    uh[bu + 128]  = (id == 1) ? hh : (_Float16)0.f;
    ul[bu + 128]  = (id == 1) ? hl : (_Float16)0.f;
    uh[bu + 2048] = (id == 2) ? hh : (_Float16)0.f;
    ul[bu + 2048] = (id == 2) ? hl : (_Float16)0.f;
    uh[bu + 2176] = (id == 3) ? hh : (_Float16)0.f;
    ul[bu + 2176] = (id == 3) ? hl : (_Float16)0.f;
  }
}

// ---------------- K3: MFMA convT partial (cp-split grid + kc-split waves) ----------------
// up[o,y,x] = sum_{cp,ky,kx} W0[cp][o][ky][kx] * u[cp, y+2-ky, x+2-kx]
// grid (64 b, 4 quad, 2 ks) = 512 blocks, 128 thr = 2 waves (kc 0/1 of this ks's 64 cp).
// Wave: m = 4 mt (all 64 o), K = 32, n = 4 nt (64 pos). LDS C-combine -> upPart[ks].
__global__ __launch_bounds__(128, 2) void k_convT(
    const _Float16* __restrict__ uh, const _Float16* __restrict__ ul,
    const _Float16* __restrict__ wA1h, const _Float16* __restrict__ wA1l,
    float* __restrict__ upPart) {
  __shared__ __align__(16) _Float16 sm[2 * 10368];  // [plane][pos 144][cp 64+8pad]
  int b = blockIdx.x, q = blockIdx.y, ks = blockIdx.z, tid = threadIdx.x;
  int qy = q >> 1, qx = q & 1;

  for (int i = tid; i < 4608; i += 128) {
    int pos = i >> 5, u2 = i & 31;
    int ty = pos / 12, tx = pos % 12;
    int gy = qy * 8 - 2 + ty, gx = qx * 8 - 2 + tx;
    unsigned vh = 0, vl = 0;
    if (gy >= 0 && gy < 16 && gx >= 0 && gx < 16) {
      int off = b * 32768 + (gy * 16 + gx) * 128 + ks * 64 + u2 * 2;
      vh = *(const unsigned*)(uh + off);
      vl = *(const unsigned*)(ul + off);
    }
    *(unsigned*)(sm + pos * 72 + u2 * 2) = vh;
    *(unsigned*)(sm + 10368 + pos * 72 + u2 * 2) = vl;
  }
  __syncthreads();

  int lane = tid & 63, kc = tid >> 6;
  int l16 = lane & 15, quad = lane >> 4;
  int wy = (l16 >> 1) & 1;
  int x_l = ((l16 >> 2) << 1) + (l16 & 1);

  f32x4 acch[4][4], accl[4][4];   // [nt][mt]
#pragma unroll
  for (int nt = 0; nt < 4; nt++)
#pragma unroll
    for (int mt = 0; mt < 4; mt++) {
      f32x4 z; z[0] = 0.f; z[1] = 0.f; z[2] = 0.f; z[3] = 0.f;
      acch[nt][mt] = z; accl[nt][mt] = z;
    }

  for (int tap = 0; tap < 25; tap++) {
    int ky = tap / 5, kx = tap % 5;
    int c = ks * 2 + kc;
    const _Float16* ap  = wA1h + ((tap * 4 + c) * 64 + l16) * 32 + quad * 8;
    const _Float16* alp = wA1l + ((tap * 4 + c) * 64 + l16) * 32 + quad * 8;
    half8 ah[4], al[4];
#pragma unroll
    for (int mt = 0; mt < 4; mt++) {
      ah[mt] = *(const half8*)(ap + mt * 512);
      al[mt] = *(const half8*)(alp + mt * 512);
    }
#pragma unroll
    for (int nt = 0; nt < 4; nt++) {
      int pos = (2 * nt + wy + 4 - ky) * 12 + x_l + 4 - kx;
      half8 bh = *(const half8*)(sm + pos * 72 + kc * 32 + quad * 8);
      half8 bl = *(const half8*)(sm + 10368 + pos * 72 + kc * 32 + quad * 8);
#pragma unroll
      for (int mt = 0; mt < 4; mt++) {
        acch[nt][mt] = MFMA_F16(ah[mt], bh, acch[nt][mt]);
        accl[nt][mt] = MFMA_F16(al[mt], bh, accl[nt][mt]);
        accl[nt][mt] = MFMA_F16(ah[mt], bl, accl[nt][mt]);
      }
    }
  }

  // combine planes, write K-partials to LDS C-regions [o 64][66]
  __syncthreads();
  float* Cb = (float*)sm;
  float* myC = Cb + kc * 4224;
#pragma unroll
  for (int nt = 0; nt < 4; nt++) {
    int p64 = (2 * nt + wy) * 8 + x_l;
#pragma unroll
    for (int mt = 0; mt < 4; mt++) {
#pragma unroll
      for (int r = 0; r < 4; r++) {
        myC[(mt * 16 + quad * 4 + r) * 66 + p64] = acch[nt][mt][r] + LO_SCALE * accl[nt][mt][r];
      }
    }
  }
  __syncthreads();

  // store summed partial for this ks
  float* op = upPart + ks * 1048576 + b * 16384;
  for (int it = 0; it < 32; it++) {
    int idx = it * 128 + tid;          // 4096 = 64 o x 64 pos
    int o = idx >> 6, p = idx & 63;
    float v = Cb[o * 66 + p] + Cb[4224 + o * 66 + p];
    int y = qy * 8 + (p >> 3), x = qx * 8 + (p & 7);
    op[o * 256 + y * 16 + x] = v;
  }
}

// ---------------- K3b: s2_new = rho(p2 + up0 + up1) ----------------
__global__ __launch_bounds__(256) void k_s2comb(
    const float* __restrict__ p2, const float* __restrict__ a,
    const float* __restrict__ b, float* __restrict__ s2new) {
  int i = blockIdx.x * 256 + threadIdx.x;   // over 262144 float4s
  float4 p = ((const float4*)p2)[i];
  float4 av = ((const float4*)a)[i];
  float4 bv = ((const float4*)b)[i];
  float4 o;
  o.x = rho_(p.x + av.x + bv.x);
  o.y = rho_(p.y + av.y + bv.y);
  o.z = rho_(p.z + av.z + bv.z);
  o.w = rho_(p.w + av.w + bv.w);
  ((float4*)s2new)[i] = o;
}

// ---------------- K5: s0_new = rho(s1_old_flat @ fc_w^T + fc_b) ----------------
__global__ __launch_bounds__(256) void k_s0fc(
    const float* __restrict__ s1old, const float* __restrict__ fcw,
    const float* __restrict__ fcb, float* __restrict__ s0new) {
  __shared__ float red[10][256];
  int b = blockIdx.x, tid = threadIdx.x;
  float acc[10];
#pragma unroll
  for (int o = 0; o < 10; o++) acc[o] = 0.f;
  const float* sb = s1old + b * 8192;
  for (int i = tid; i < 8192; i += 256) {
    float v = sb[i];
#pragma unroll
    for (int o = 0; o < 10; o++) acc[o] += v * fcw[o * 8192 + i];
  }
#pragma unroll
  for (int o = 0; o < 10; o++) red[o][tid] = acc[o];
  __syncthreads();
  for (int s = 128; s > 0; s >>= 1) {
    if (tid < s) {
#pragma unroll
      for (int o = 0; o < 10; o++) red[o][tid] += red[o][tid + s];
    }
    __syncthreads();
  }
  if (tid < 10) s0new[b * 10 + tid] = rho_(red[tid][0] + fcb[tid]);
}

extern "C" void kernel_launch(void* const* d_in, const int* in_sizes, int n_in,
                              void* d_out, int out_size, void* d_ws, size_t ws_size,
                              hipStream_t stream) {
  const float* data   = (const float*)d_in[0];
  const float* s0init = (const float*)d_in[1];   // zeros
  const float* s1init = (const float*)d_in[2];   // zeros
  const float* s2init = (const float*)d_in[3];   // zeros
  const float* conv0w = (const float*)d_in[4];
  const float* conv0b = (const float*)d_in[5];
  const float* conv1w = (const float*)d_in[6];
  const float* conv1b = (const float*)d_in[7];
  const float* fcw    = (const float*)d_in[8];
  const float* fcb    = (const float*)d_in[9];

  // workspace layout (~30 MB)
  float* p = (float*)d_ws;
  float* s0buf[2] = {p, p + 640};            p += 1280;
  float* s1buf[2] = {p, p + 524288};         p += 1048576;
  float* s2buf[2] = {p, p + 1048576};        p += 2097152;
  float* p2 = p;                             p += 1048576;
  float* upPart = p;                         p += 2097152;   // 2 x 1M floats
  _Float16* hq = (_Float16*)p;
  _Float16* uh   = hq;                       hq += 2097152;  // [b][pos 256][cp 128]
  _Float16* ul   = hq;                       hq += 2097152;
  _Float16* wA0h = hq;                       hq += 204800;
  _Float16* wA0l = hq;                       hq += 204800;
  _Float16* wA1h = hq;                       hq += 204800;
  _Float16* wA1l = hq;                       hq += 204800;

  k_wprep<<<800, 256, 0, stream>>>(conv0w, wA0h, wA0l, wA1h, wA1l);
  k_p2<<<dim3(64, 4), 256, 0, stream>>>(data, conv1w, conv1b, p2);

  const float* s0o = s0init;
  const float* s1o = s1init;
  const float* s2o = s2init;
  float* outp = (float*)d_out;

  for (int t = 0; t < 10; t++) {
    int nb = t & 1;
    float* s0w = s0buf[nb];
    float* s1w = s1buf[nb];
    float* s2w = s2buf[nb];

    // conv0(s2_old) + pool/argmax; s1_new = rho(p1 + fc^T(s0_old)); u = split(unpool(s1_old, idx))
    k_conv0<<<dim3(64, 4, 2), 128, 0, stream>>>(s2o, wA0h, wA0l, conv0b, s1o, s0o, fcw, s1w, uh, ul);
    // s0_new = rho(fc(s1_old))
    k_s0fc<<<64, 256, 0, stream>>>(s1o, fcw, fcb, s0w);
    // convT partials + combine: s2_new = rho(p2 + up0 + up1)
    k_convT<<<dim3(64, 4, 2), 128, 0, stream>>>(uh, ul, wA1h, wA1l, upPart);
    k_s2comb<<<1024, 256, 0, stream>>>(p2, upPart, upPart + 1048576, s2w);

    s0o = s0w; s1o = s1w; s2o = s2w;

    if (t == 6) {   // PRED_T snapshot (post-update states)
      hipMemcpyAsync(outp + 1573504, s0w, 640 * sizeof(float),     hipMemcpyDeviceToDevice, stream);
      hipMemcpyAsync(outp + 1574144, s1w, 524288 * sizeof(float),  hipMemcpyDeviceToDevice, stream);
      hipMemcpyAsync(outp + 2098432, s2w, 1048576 * sizeof(float), hipMemcpyDeviceToDevice, stream);
    }
  }

  // final states
  hipMemcpyAsync(outp + 0,      s0o, 640 * sizeof(float),     hipMemcpyDeviceToDevice, stream);
  hipMemcpyAsync(outp + 640,    s1o, 524288 * sizeof(float),  hipMemcpyDeviceToDevice, stream);
  hipMemcpyAsync(outp + 524928, s2o, 1048576 * sizeof(float), hipMemcpyDeviceToDevice, stream);
}

// Round 10
// 1034.596 us; speedup vs baseline: 1.4000x; 1.1303x over previous
//
#include <hip/hip_runtime.h>

// convEP: 10-step EP relaxation, MFMA fp16 2-way-split convs (fp32-equivalent).
//   s0' = rho(fc(s1));  s1' = rho(pool(conv0(s2)) + fc^T(s0));  s2' = rho(p2 + convT(unpool(s1, idx1)))
// fp32 x = xh + 2^-12*xl' (fp16 planes, lo pre-scaled 2^12 to stay fp16-normal).
// x*y ~= xh*yh + 2^-12*(xh*yl' + xl'*yh); acc_hi/acc_lo separate, combined at epilogue.
// MFMA 16x16x32_f16: A[m=l16][k=quad*8+j], B[k=quad*8+j][n=l16], C/D: col=l16, row=quad*4+reg.
// R10: 512-thr blocks (8 waves = kc2 x quarter4), full image in LDS (no halo; border via
// cndmask-zeroed B-frags), tap-group split tg=2 across blocks -> 2 waves/SIMD at low A-rate.
// Tap partials (fp32) summed by combine kernels carrying the epilogues.

typedef _Float16 half8 __attribute__((ext_vector_type(8)));
typedef float f32x4 __attribute__((ext_vector_type(4)));
#define MFMA_F16(A, B, C) __builtin_amdgcn_mfma_f32_16x16x32_f16((A), (B), (C), 0, 0, 0)
#define LO_SCALE 2.44140625e-4f   // 2^-12

static __device__ __forceinline__ float rho_(float x) {
  return fminf(fmaxf(x, 0.0f), 1.0f);
}
static __device__ __forceinline__ void split2(float v, _Float16& h, _Float16& l) {
  if (fabsf(v) < 6.1035156e-5f) {
    h = (_Float16)0.f;
    l = (_Float16)(v * 4096.f);
  } else {
    h = (_Float16)v;
    l = (_Float16)((v - (float)h) * 4096.f);
  }
}
static __device__ __forceinline__ half8 hzero() {
  half8 z;
#pragma unroll
  for (int j = 0; j < 8; j++) z[j] = (_Float16)0.f;
  return z;
}

// ---------------- K0: one-time weight split+transpose ----------------
// wA0[((tap*2+kc)*128 + co)*32 + cik] = conv0w[co][kc*32+cik][tap]
// wA1[((tap*4+c )*64  + o )*32 + cpk] = conv0w[(c*32+cpk)][o][tap]
__global__ __launch_bounds__(256) void k_wprep(
    const float* __restrict__ w0,
    _Float16* __restrict__ wA0h, _Float16* __restrict__ wA0l,
    _Float16* __restrict__ wA1h, _Float16* __restrict__ wA1l) {
  int i = blockIdx.x * 256 + threadIdx.x;
  if (i >= 204800) return;
  {
    int cik = i & 31, t1 = i >> 5;
    int co = t1 & 127, t2 = t1 >> 7;
    int ck = t2 & 1, tap = t2 >> 1;
    float v = w0[(co * 64 + ck * 32 + cik) * 25 + tap];
    _Float16 h, l; split2(v, h, l);
    wA0h[i] = h; wA0l[i] = l;
  }
  {
    int cpk = i & 31, t1 = i >> 5;
    int o = t1 & 63, t2 = t1 >> 6;
    int c = t2 & 3, tap = t2 >> 2;
    float v = w0[((c * 32 + cpk) * 64 + o) * 25 + tap];
    _Float16 h, l; split2(v, h, l);
    wA1h[i] = h; wA1l[i] = l;
  }
}

// ---------------- K1: p2 = maxpool2x2(conv2d(data, conv1_w) + conv1_b) (once, fp32) ----------------
__global__ __launch_bounds__(256) void k_p2(
    const float* __restrict__ data, const float* __restrict__ w,
    const float* __restrict__ bias, float* __restrict__ p2) {
  __shared__ float ld[3][36][36];
  __shared__ float lw[16][80];
  __shared__ float lb[16];
  int b = blockIdx.x, cg = blockIdx.y, tid = threadIdx.x;
  for (int i = tid; i < 3 * 36 * 36; i += 256) {
    int ci = i / 1296, rem = i % 1296, y = rem / 36, x = rem % 36;
    int gy = y - 2, gx = x - 2;
    float v = 0.f;
    if (gy >= 0 && gy < 32 && gx >= 0 && gx < 32)
      v = data[(b * 3 + ci) * 1024 + gy * 32 + gx];
    ld[ci][y][x] = v;
  }
  for (int i = tid; i < 16 * 75; i += 256) {
    int co = i / 75, k = i % 75;
    lw[co][k] = w[(cg * 16 + co) * 75 + k];
  }
  if (tid < 16) lb[tid] = bias[cg * 16 + tid];
  __syncthreads();
  int ph = tid >> 4, pw = tid & 15;
  int ry = 2 * ph, rx = 2 * pw;
  for (int co = 0; co < 16; co++) {
    float bv = lb[co];
    float a00 = bv, a01 = bv, a10 = bv, a11 = bv;
    for (int ci = 0; ci < 3; ci++) {
#pragma unroll
      for (int ky = 0; ky < 5; ky++) {
#pragma unroll
        for (int kx = 0; kx < 5; kx++) {
          float wv = lw[co][(ci * 5 + ky) * 5 + kx];
          a00 += wv * ld[ci][ry + ky][rx + kx];
          a01 += wv * ld[ci][ry + ky][rx + kx + 1];
          a10 += wv * ld[ci][ry + ky + 1][rx + kx];
          a11 += wv * ld[ci][ry + ky + 1][rx + kx + 1];
        }
      }
    }
    float m = fmaxf(fmaxf(a00, a01), fmaxf(a10, a11));
    p2[((b * 64 + cg * 16 + co) * 16 + ph) * 16 + pw] = m;
  }
}

// ---------------- K2: conv0 GEMM (tap-group partial) ----------------
// grid (64 b, 2 cg, 2 tg) = 256 blocks, 512 thr = 8 waves = kc(2) x qh(4).
// Wave: m=4 mt (cg's 64 co), n=4 nt (qh's 4 rows = 64 pos), K=32 (kc), taps = tg's 13/12.
// Full image in LDS (no halo); border taps -> zeroed B-frags. Bias in (kc0,tg0).
// P0[tg][b][co 128][pos 256] fp32 partial.
__global__ __launch_bounds__(512, 2) void k_conv0g(
    const float* __restrict__ s2,
    const _Float16* __restrict__ wA0h, const _Float16* __restrict__ wA0l,
    const float* __restrict__ b0, float* __restrict__ P0) {
  __shared__ __align__(16) _Float16 sm[36864];   // 2 planes x [pos 256][ci 64+8] = 73728 B
  int b = blockIdx.x, cg = blockIdx.y, tg = blockIdx.z, tid = threadIdx.x;

  const float* s2b = s2 + b * 16384;
  for (int i = tid; i < 16384; i += 512) {
    int ci = i >> 8, pos = i & 255;     // linear read: ci*256+pos == i
    float v = s2b[i];
    _Float16 h, l; split2(v, h, l);
    sm[pos * 72 + ci] = h;
    sm[18432 + pos * 72 + ci] = l;
  }
  __syncthreads();

  int lane = tid & 63, w = tid >> 6;
  int kc = w & 1, qh = w >> 1;
  int l16 = lane & 15, quad = lane >> 4;
  int wy = (l16 >> 1) & 1;
  int x_l = ((l16 >> 2) << 1) + (l16 & 1);

  f32x4 acch[4][4], accl[4][4];   // [nt][mt]
#pragma unroll
  for (int nt = 0; nt < 4; nt++)
#pragma unroll
    for (int mt = 0; mt < 4; mt++) {
      f32x4 z; z[0] = 0.f; z[1] = 0.f; z[2] = 0.f; z[3] = 0.f;
      accl[nt][mt] = z;
      if (kc == 0 && tg == 0) {
        int cb = cg * 64 + mt * 16 + quad * 4;
        f32x4 bi; bi[0] = b0[cb]; bi[1] = b0[cb + 1]; bi[2] = b0[cb + 2]; bi[3] = b0[cb + 3];
        acch[nt][mt] = bi;
      } else {
        acch[nt][mt] = z;
      }
    }

  int tap0 = tg * 13, tap1 = tg ? 25 : 13;
  for (int tap = tap0; tap < tap1; tap++) {
    int ky = tap / 5, kx = tap % 5;
    const _Float16* ap  = wA0h + ((tap * 2 + kc) * 128 + cg * 64 + l16) * 32 + quad * 8;
    const _Float16* alp = wA0l + ((tap * 2 + kc) * 128 + cg * 64 + l16) * 32 + quad * 8;
    half8 ah[4], al[4];
#pragma unroll
    for (int mt = 0; mt < 4; mt++) {
      ah[mt] = *(const half8*)(ap + mt * 512);
      al[mt] = *(const half8*)(alp + mt * 512);
    }
#pragma unroll
    for (int nt = 0; nt < 4; nt++) {
      int y = qh * 4 + (nt >> 1) * 2 + wy;
      int x = (nt & 1) * 8 + x_l;
      int iy = y + ky - 2, ix = x + kx - 2;
      bool oob = ((unsigned)iy > 15u) || ((unsigned)ix > 15u);
      int iyc = min(max(iy, 0), 15), ixc = min(max(ix, 0), 15);
      int pos = iyc * 16 + ixc;
      half8 bh = *(const half8*)(sm + pos * 72 + kc * 32 + quad * 8);
      half8 bl = *(const half8*)(sm + 18432 + pos * 72 + kc * 32 + quad * 8);
      if (oob) { bh = hzero(); bl = hzero(); }
#pragma unroll
      for (int mt = 0; mt < 4; mt++) {
        acch[nt][mt] = MFMA_F16(ah[mt], bh, acch[nt][mt]);
        accl[nt][mt] = MFMA_F16(al[mt], bh, accl[nt][mt]);
        accl[nt][mt] = MFMA_F16(ah[mt], bl, accl[nt][mt]);
      }
    }
  }

  // kc-combine via LDS C [co 64][260] (66560 B, reuses sm)
  __syncthreads();
  float* C = (float*)sm;
  if (kc == 0) {
#pragma unroll
    for (int nt = 0; nt < 4; nt++) {
      int pos = (qh * 4 + (nt >> 1) * 2 + wy) * 16 + (nt & 1) * 8 + x_l;
#pragma unroll
      for (int mt = 0; mt < 4; mt++)
#pragma unroll
        for (int r = 0; r < 4; r++)
          C[(mt * 16 + quad * 4 + r) * 260 + pos] = acch[nt][mt][r] + LO_SCALE * accl[nt][mt][r];
    }
  }
  __syncthreads();
  if (kc == 1) {
#pragma unroll
    for (int nt = 0; nt < 4; nt++) {
      int pos = (qh * 4 + (nt >> 1) * 2 + wy) * 16 + (nt & 1) * 8 + x_l;
#pragma unroll
      for (int mt = 0; mt < 4; mt++)
#pragma unroll
        for (int r = 0; r < 4; r++) {
          int a = (mt * 16 + quad * 4 + r) * 260 + pos;
          C[a] += acch[nt][mt][r] + LO_SCALE * accl[nt][mt][r];
        }
    }
  }
  __syncthreads();

  float* op = P0 + tg * 2097152 + (b * 128 + cg * 64) * 256;
  for (int m = tid; m < 16384; m += 512) {
    int co = m >> 8, pos = m & 255;
    op[co * 256 + pos] = C[co * 260 + pos];
  }
}

// ---------------- K2b: conv0 combine: pool/argmax + s1 update + u split-write ----------------
// grid (64 b, 32), 256 thr: idx in [0,8192) = co(128) x win(64). s1 updated in place (elementwise).
__global__ __launch_bounds__(256) void k_c0comb(
    const float* __restrict__ P0, const float* __restrict__ s1old,
    const float* __restrict__ s0old, const float* __restrict__ fcw,
    float* __restrict__ s1new, _Float16* __restrict__ uh, _Float16* __restrict__ ul) {
  int b = blockIdx.x;
  int idx = blockIdx.y * 256 + threadIdx.x;
  int co = idx >> 6, win = idx & 63;
  int ph = win >> 3, pw = win & 7;
  int pos0 = ph * 32 + pw * 2;
  const float* pa = P0 + b * 32768 + co * 256;
  const float* pb = pa + 2097152;
  float v0 = pa[pos0]      + pb[pos0];
  float v1 = pa[pos0 + 1]  + pb[pos0 + 1];
  float v2 = pa[pos0 + 16] + pb[pos0 + 16];
  float v3 = pa[pos0 + 17] + pb[pos0 + 17];
  float m0 = v0; int id = 0;
  if (v1 > m0) { m0 = v1; id = 1; }
  if (v2 > m0) { m0 = v2; id = 2; }
  if (v3 > m0) { m0 = v3; id = 3; }
  int j = co * 64 + ph * 8 + pw;
  float a = m0;
#pragma unroll
  for (int k = 0; k < 10; k++) a += s0old[b * 10 + k] * fcw[k * 8192 + j];
  float sv = s1old[b * 8192 + j];
  s1new[b * 8192 + j] = rho_(a);
  _Float16 hh, hl; split2(sv, hh, hl);
  int bu = (b * 256 + pos0) * 128 + co;
  _Float16 z = (_Float16)0.f;
  uh[bu]        = (id == 0) ? hh : z;
  ul[bu]        = (id == 0) ? hl : z;
  uh[bu + 128]  = (id == 1) ? hh : z;
  ul[bu + 128]  = (id == 1) ? hl : z;
  uh[bu + 2048] = (id == 2) ? hh : z;
  ul[bu + 2048] = (id == 2) ? hl : z;
  uh[bu + 2176] = (id == 3) ? hh : z;
  ul[bu + 2176] = (id == 3) ? hl : z;
}

// ---------------- K3: convT GEMM (cp-half x tap-group partial) ----------------
// up[o,y,x] = sum_{cp,ky,kx} W0[cp][o][ky][kx] * u[cp, y+2-ky, x+2-kx]
// grid (64 b, 2 ks, 2 tg) = 256 blocks, 512 thr = 8 waves = kc(2) x qh(4).
// Wave: m=4 mt (all 64 o), n=4 nt, K=32 (kc of ks's 64 cp). P1[(tg*2+ks)][b][o][pos].
__global__ __launch_bounds__(512, 2) void k_convTg(
    const _Float16* __restrict__ uh, const _Float16* __restrict__ ul,
    const _Float16* __restrict__ wA1h, const _Float16* __restrict__ wA1l,
    float* __restrict__ P1) {
  __shared__ __align__(16) _Float16 sm[36864];
  int b = blockIdx.x, ks = blockIdx.y, tg = blockIdx.z, tid = threadIdx.x;

  for (int i = tid; i < 8192; i += 512) {
    int pos = i >> 5, c2 = i & 31;
    int off = b * 32768 + pos * 128 + ks * 64 + c2 * 2;
    *(unsigned*)(sm + pos * 72 + c2 * 2) = *(const unsigned*)(uh + off);
    *(unsigned*)(sm + 18432 + pos * 72 + c2 * 2) = *(const unsigned*)(ul + off);
  }
  __syncthreads();

  int lane = tid & 63, w = tid >> 6;
  int kc = w & 1, qh = w >> 1;
  int l16 = lane & 15, quad = lane >> 4;
  int wy = (l16 >> 1) & 1;
  int x_l = ((l16 >> 2) << 1) + (l16 & 1);

  f32x4 acch[4][4], accl[4][4];
#pragma unroll
  for (int nt = 0; nt < 4; nt++)
#pragma unroll
    for (int mt = 0; mt < 4; mt++) {
      f32x4 z; z[0] = 0.f; z[1] = 0.f; z[2] = 0.f; z[3] = 0.f;
      acch[nt][mt] = z; accl[nt][mt] = z;
    }

  int tap0 = tg * 13, tap1 = tg ? 25 : 13;
  for (int tap = tap0; tap < tap1; tap++) {
    int ky = tap / 5, kx = tap % 5;
    int c = ks * 2 + kc;
    const _Float16* ap  = wA1h + ((tap * 4 + c) * 64 + l16) * 32 + quad * 8;
    const _Float16* alp = wA1l + ((tap * 4 + c) * 64 + l16) * 32 + quad * 8;
    half8 ah[4], al[4];
#pragma unroll
    for (int mt = 0; mt < 4; mt++) {
      ah[mt] = *(const half8*)(ap + mt * 512);
      al[mt] = *(const half8*)(alp + mt * 512);
    }
#pragma unroll
    for (int nt = 0; nt < 4; nt++) {
      int y = qh * 4 + (nt >> 1) * 2 + wy;
      int x = (nt & 1) * 8 + x_l;
      int iy = y + 2 - ky, ix = x + 2 - kx;
      bool oob = ((unsigned)iy > 15u) || ((unsigned)ix > 15u);
      int iyc = min(max(iy, 0), 15), ixc = min(max(ix, 0), 15);
      int pos = iyc * 16 + ixc;
      half8 bh = *(const half8*)(sm + pos * 72 + kc * 32 + quad * 8);
      half8 bl = *(const half8*)(sm + 18432 + pos * 72 + kc * 32 + quad * 8);
      if (oob) { bh = hzero(); bl = hzero(); }
#pragma unroll
      for (int mt = 0; mt < 4; mt++) {
        acch[nt][mt] = MFMA_F16(ah[mt], bh, acch[nt][mt]);
        accl[nt][mt] = MFMA_F16(al[mt], bh, accl[nt][mt]);
        accl[nt][mt] = MFMA_F16(ah[mt], bl, accl[nt][mt]);
      }
    }
  }

  __syncthreads();
  float* C = (float*)sm;   // [o 64][260]
  if (kc == 0) {
#pragma unroll
    for (int nt = 0; nt < 4; nt++) {
      int pos = (qh * 4 + (nt >> 1) * 2 + wy) * 16 + (nt & 1) * 8 + x_l;
#pragma unroll
      for (int mt = 0; mt < 4; mt++)
#pragma unroll
        for (int r = 0; r < 4; r++)
          C[(mt * 16 + quad * 4 + r) * 260 + pos] = acch[nt][mt][r] + LO_SCALE * accl[nt][mt][r];
    }
  }
  __syncthreads();
  if (kc == 1) {
#pragma unroll
    for (int nt = 0; nt < 4; nt++) {
      int pos = (qh * 4 + (nt >> 1) * 2 + wy) * 16 + (nt & 1) * 8 + x_l;
#pragma unroll
      for (int mt = 0; mt < 4; mt++)
#pragma unroll
        for (int r = 0; r < 4; r++) {
          int a = (mt * 16 + quad * 4 + r) * 260 + pos;
          C[a] += acch[nt][mt][r] + LO_SCALE * accl[nt][mt][r];
        }
    }
  }
  __syncthreads();

  float* op = P1 + (tg * 2 + ks) * 1048576 + b * 16384;
  for (int m = tid; m < 16384; m += 512) {
    int o = m >> 8, pos = m & 255;
    op[o * 256 + pos] = C[o * 260 + pos];
  }
}

// ---------------- K3b: s2 = rho(p2 + P1[0]+P1[1]+P1[2]+P1[3]) (in place ok) ----------------
__global__ __launch_bounds__(256) void k_cTcomb(
    const float* __restrict__ p2, const float* __restrict__ P1,
    float* __restrict__ s2new) {
  int i = blockIdx.x * 256 + threadIdx.x;   // over 262144 float4s
  float4 p = ((const float4*)p2)[i];
  float4 a0 = ((const float4*)P1)[i];
  float4 a1 = ((const float4*)(P1 + 1048576))[i];
  float4 a2 = ((const float4*)(P1 + 2097152))[i];
  float4 a3 = ((const float4*)(P1 + 3145728))[i];
  float4 o;
  o.x = rho_(p.x + a0.x + a1.x + a2.x + a3.x);
  o.y = rho_(p.y + a0.y + a1.y + a2.y + a3.y);
  o.z = rho_(p.z + a0.z + a1.z + a2.z + a3.z);
  o.w = rho_(p.w + a0.w + a1.w + a2.w + a3.w);
  ((float4*)s2new)[i] = o;
}

// ---------------- K5: s0_new = rho(s1_old_flat @ fc_w^T + fc_b) ----------------
__global__ __launch_bounds__(256) void k_s0fc(
    const float* __restrict__ s1old, const float* __restrict__ fcw,
    const float* __restrict__ fcb, float* __restrict__ s0new) {
  __shared__ float red[10][256];
  int b = blockIdx.x, tid = threadIdx.x;
  float acc[10];
#pragma unroll
  for (int o = 0; o < 10; o++) acc[o] = 0.f;
  const float* sb = s1old + b * 8192;
  for (int i = tid; i < 8192; i += 256) {
    float v = sb[i];
#pragma unroll
    for (int o = 0; o < 10; o++) acc[o] += v * fcw[o * 8192 + i];
  }
#pragma unroll
  for (int o = 0; o < 10; o++) red[o][tid] = acc[o];
  __syncthreads();
  for (int s = 128; s > 0; s >>= 1) {
    if (tid < s) {
#pragma unroll
      for (int o = 0; o < 10; o++) red[o][tid] += red[o][tid + s];
    }
    __syncthreads();
  }
  if (tid < 10) s0new[b * 10 + tid] = rho_(red[tid][0] + fcb[tid]);
}

extern "C" void kernel_launch(void* const* d_in, const int* in_sizes, int n_in,
                              void* d_out, int out_size, void* d_ws, size_t ws_size,
                              hipStream_t stream) {
  const float* data   = (const float*)d_in[0];
  const float* s0init = (const float*)d_in[1];   // zeros
  const float* s1init = (const float*)d_in[2];   // zeros
  const float* s2init = (const float*)d_in[3];   // zeros
  const float* conv0w = (const float*)d_in[4];
  const float* conv0b = (const float*)d_in[5];
  const float* conv1w = (const float*)d_in[6];
  const float* conv1b = (const float*)d_in[7];
  const float* fcw    = (const float*)d_in[8];
  const float* fcb    = (const float*)d_in[9];

  // workspace (~37.4 MB): s1/s2 single-buffered (elementwise in-place updates);
  // P shared between conv0 partials (2x2.1M) and convT partials (4x1.05M).
  float* p = (float*)d_ws;
  float* s0buf[2] = {p, p + 640};            p += 1280;
  float* s1ws = p;                           p += 524288;
  float* s2ws = p;                           p += 1048576;
  float* p2 = p;                             p += 1048576;
  float* P  = p;                             p += 4194304;
  _Float16* hq = (_Float16*)p;
  _Float16* uh   = hq;                       hq += 2097152;  // [b][pos 256][cp 128]
  _Float16* ul   = hq;                       hq += 2097152;
  _Float16* wA0h = hq;                       hq += 204800;
  _Float16* wA0l = hq;                       hq += 204800;
  _Float16* wA1h = hq;                       hq += 204800;
  _Float16* wA1l = hq;                       hq += 204800;

  k_wprep<<<800, 256, 0, stream>>>(conv0w, wA0h, wA0l, wA1h, wA1l);
  k_p2<<<dim3(64, 4), 256, 0, stream>>>(data, conv1w, conv1b, p2);

  const float* s0o = s0init;
  const float* s1o = s1init;
  const float* s2o = s2init;
  float* outp = (float*)d_out;

  for (int t = 0; t < 10; t++) {
    float* s0w = s0buf[t & 1];

    // conv0 GEMM partials from s2_old
    k_conv0g<<<dim3(64, 2, 2), 512, 0, stream>>>(s2o, wA0h, wA0l, conv0b, P);
    // s0_new = rho(fc(s1_old))  (must read s1_old before c0comb overwrites it)
    k_s0fc<<<64, 256, 0, stream>>>(s1o, fcw, fcb, s0w);
    // combine: pool/argmax; s1 = rho(p1 + fc^T(s0_old)); u = split(unpool(s1_old, idx))
    k_c0comb<<<dim3(64, 32), 256, 0, stream>>>(P, s1o, s0o, fcw, s1ws, uh, ul);
    // convT GEMM partials + combine: s2 = rho(p2 + sum partials)
    k_convTg<<<dim3(64, 2, 2), 512, 0, stream>>>(uh, ul, wA1h, wA1l, P);
    k_cTcomb<<<1024, 256, 0, stream>>>(p2, P, s2ws);

    s0o = s0w; s1o = s1ws; s2o = s2ws;

    if (t == 6) {   // PRED_T snapshot (post-update states)
      hipMemcpyAsync(outp + 1573504, s0w,  640 * sizeof(float),     hipMemcpyDeviceToDevice, stream);
      hipMemcpyAsync(outp + 1574144, s1ws, 524288 * sizeof(float),  hipMemcpyDeviceToDevice, stream);
      hipMemcpyAsync(outp + 2098432, s2ws, 1048576 * sizeof(float), hipMemcpyDeviceToDevice, stream);
    }
  }

  // final states
  hipMemcpyAsync(outp + 0,      s0o, 640 * sizeof(float),     hipMemcpyDeviceToDevice, stream);
  hipMemcpyAsync(outp + 640,    s1o, 524288 * sizeof(float),  hipMemcpyDeviceToDevice, stream);
  hipMemcpyAsync(outp + 524928, s2o, 1048576 * sizeof(float), hipMemcpyDeviceToDevice, stream);
}

// Round 11
// 1020.688 us; speedup vs baseline: 1.4190x; 1.0136x over previous
//
#include <hip/hip_runtime.h>

// convEP: 10-step EP relaxation, MFMA fp16 2-way-split convs (fp32-equivalent).
//   s0' = rho(fc(s1));  s1' = rho(pool(conv0(s2)) + fc^T(s0));  s2' = rho(p2 + convT(unpool(s1, idx1)))
// fp32 x = xh + 2^-12*xl' (fp16 planes, lo pre-scaled 2^12 to stay fp16-normal).
// x*y ~= xh*yh + 2^-12*(xh*yl' + xl'*yh); acc_hi/acc_lo separate, combined at epilogue.
// MFMA 16x16x32_f16: A[m=l16][k=quad*8+j], B[k=quad*8+j][n=l16], C/D: col=l16, row=quad*4+reg.
// R11: mt=2 per wave (acc 64 VGPR -> 4 waves/SIMD), m-dim split across blocks:
// grid 512 both convs, LDS 73.7KB -> 2 blocks/CU co-resident (prologue/epilogue overlap MFMA).

typedef _Float16 half8 __attribute__((ext_vector_type(8)));
typedef float f32x4 __attribute__((ext_vector_type(4)));
#define MFMA_F16(A, B, C) __builtin_amdgcn_mfma_f32_16x16x32_f16((A), (B), (C), 0, 0, 0)
#define LO_SCALE 2.44140625e-4f   // 2^-12

static __device__ __forceinline__ float rho_(float x) {
  return fminf(fmaxf(x, 0.0f), 1.0f);
}
static __device__ __forceinline__ void split2(float v, _Float16& h, _Float16& l) {
  if (fabsf(v) < 6.1035156e-5f) {
    h = (_Float16)0.f;
    l = (_Float16)(v * 4096.f);
  } else {
    h = (_Float16)v;
    l = (_Float16)((v - (float)h) * 4096.f);
  }
}
static __device__ __forceinline__ half8 hzero() {
  half8 z;
#pragma unroll
  for (int j = 0; j < 8; j++) z[j] = (_Float16)0.f;
  return z;
}

// ---------------- K0: one-time weight split+transpose ----------------
// wA0[((tap*2+kc)*128 + co)*32 + cik] = conv0w[co][kc*32+cik][tap]
// wA1[((tap*4+c )*64  + o )*32 + cpk] = conv0w[(c*32+cpk)][o][tap]
__global__ __launch_bounds__(256) void k_wprep(
    const float* __restrict__ w0,
    _Float16* __restrict__ wA0h, _Float16* __restrict__ wA0l,
    _Float16* __restrict__ wA1h, _Float16* __restrict__ wA1l) {
  int i = blockIdx.x * 256 + threadIdx.x;
  if (i >= 204800) return;
  {
    int cik = i & 31, t1 = i >> 5;
    int co = t1 & 127, t2 = t1 >> 7;
    int ck = t2 & 1, tap = t2 >> 1;
    float v = w0[(co * 64 + ck * 32 + cik) * 25 + tap];
    _Float16 h, l; split2(v, h, l);
    wA0h[i] = h; wA0l[i] = l;
  }
  {
    int cpk = i & 31, t1 = i >> 5;
    int o = t1 & 63, t2 = t1 >> 6;
    int c = t2 & 3, tap = t2 >> 2;
    float v = w0[((c * 32 + cpk) * 64 + o) * 25 + tap];
    _Float16 h, l; split2(v, h, l);
    wA1h[i] = h; wA1l[i] = l;
  }
}

// ---------------- K1: p2 = maxpool2x2(conv2d(data, conv1_w) + conv1_b) (once, fp32) ----------------
__global__ __launch_bounds__(256) void k_p2(
    const float* __restrict__ data, const float* __restrict__ w,
    const float* __restrict__ bias, float* __restrict__ p2) {
  __shared__ float ld[3][36][36];
  __shared__ float lw[16][80];
  __shared__ float lb[16];
  int b = blockIdx.x, cg = blockIdx.y, tid = threadIdx.x;
  for (int i = tid; i < 3 * 36 * 36; i += 256) {
    int ci = i / 1296, rem = i % 1296, y = rem / 36, x = rem % 36;
    int gy = y - 2, gx = x - 2;
    float v = 0.f;
    if (gy >= 0 && gy < 32 && gx >= 0 && gx < 32)
      v = data[(b * 3 + ci) * 1024 + gy * 32 + gx];
    ld[ci][y][x] = v;
  }
  for (int i = tid; i < 16 * 75; i += 256) {
    int co = i / 75, k = i % 75;
    lw[co][k] = w[(cg * 16 + co) * 75 + k];
  }
  if (tid < 16) lb[tid] = bias[cg * 16 + tid];
  __syncthreads();
  int ph = tid >> 4, pw = tid & 15;
  int ry = 2 * ph, rx = 2 * pw;
  for (int co = 0; co < 16; co++) {
    float bv = lb[co];
    float a00 = bv, a01 = bv, a10 = bv, a11 = bv;
    for (int ci = 0; ci < 3; ci++) {
#pragma unroll
      for (int ky = 0; ky < 5; ky++) {
#pragma unroll
        for (int kx = 0; kx < 5; kx++) {
          float wv = lw[co][(ci * 5 + ky) * 5 + kx];
          a00 += wv * ld[ci][ry + ky][rx + kx];
          a01 += wv * ld[ci][ry + ky][rx + kx + 1];
          a10 += wv * ld[ci][ry + ky + 1][rx + kx];
          a11 += wv * ld[ci][ry + ky + 1][rx + kx + 1];
        }
      }
    }
    float m = fmaxf(fmaxf(a00, a01), fmaxf(a10, a11));
    p2[((b * 64 + cg * 16 + co) * 16 + ph) * 16 + pw] = m;
  }
}

// ---------------- K2: conv0 GEMM (tap-group partial) ----------------
// grid (64 b, 4 cg, 2 tg) = 512 blocks, 512 thr = 8 waves = kc(2) x qh(4).
// Wave: m=2 mt (cg's 32 co), n=4 nt (qh's 4 rows), K=32 (kc), taps = tg's 13/12.
// Full image in LDS; border taps -> zeroed B-frags. Bias in (kc0,tg0).
// P0[tg][b][co 128][pos 256] fp32 partial (cg writes its 32-co slice).
__global__ __launch_bounds__(512, 4) void k_conv0g(
    const float* __restrict__ s2,
    const _Float16* __restrict__ wA0h, const _Float16* __restrict__ wA0l,
    const float* __restrict__ b0, float* __restrict__ P0) {
  __shared__ __align__(16) _Float16 sm[36864];   // 2 planes x [pos 256][ci 64+8] = 73728 B
  int b = blockIdx.x, cg = blockIdx.y, tg = blockIdx.z, tid = threadIdx.x;

  const float* s2b = s2 + b * 16384;
  for (int i = tid; i < 16384; i += 512) {
    int ci = i >> 8, pos = i & 255;
    float v = s2b[i];
    _Float16 h, l; split2(v, h, l);
    sm[pos * 72 + ci] = h;
    sm[18432 + pos * 72 + ci] = l;
  }
  __syncthreads();

  int lane = tid & 63, w = tid >> 6;
  int kc = w & 1, qh = w >> 1;
  int l16 = lane & 15, quad = lane >> 4;
  int wy = (l16 >> 1) & 1;
  int x_l = ((l16 >> 2) << 1) + (l16 & 1);

  f32x4 acch[4][2], accl[4][2];   // [nt][mt]
#pragma unroll
  for (int nt = 0; nt < 4; nt++)
#pragma unroll
    for (int mt = 0; mt < 2; mt++) {
      f32x4 z; z[0] = 0.f; z[1] = 0.f; z[2] = 0.f; z[3] = 0.f;
      accl[nt][mt] = z;
      if (kc == 0 && tg == 0) {
        int cb = cg * 32 + mt * 16 + quad * 4;
        f32x4 bi; bi[0] = b0[cb]; bi[1] = b0[cb + 1]; bi[2] = b0[cb + 2]; bi[3] = b0[cb + 3];
        acch[nt][mt] = bi;
      } else {
        acch[nt][mt] = z;
      }
    }

  int tap0 = tg * 13, tap1 = tg ? 25 : 13;
  for (int tap = tap0; tap < tap1; tap++) {
    int ky = tap / 5, kx = tap % 5;
    const _Float16* ap  = wA0h + ((tap * 2 + kc) * 128 + cg * 32 + l16) * 32 + quad * 8;
    const _Float16* alp = wA0l + ((tap * 2 + kc) * 128 + cg * 32 + l16) * 32 + quad * 8;
    half8 ah[2], al[2];
#pragma unroll
    for (int mt = 0; mt < 2; mt++) {
      ah[mt] = *(const half8*)(ap + mt * 512);
      al[mt] = *(const half8*)(alp + mt * 512);
    }
#pragma unroll
    for (int nt = 0; nt < 4; nt++) {
      int y = qh * 4 + (nt >> 1) * 2 + wy;
      int x = (nt & 1) * 8 + x_l;
      int iy = y + ky - 2, ix = x + kx - 2;
      bool oob = ((unsigned)iy > 15u) || ((unsigned)ix > 15u);
      int iyc = min(max(iy, 0), 15), ixc = min(max(ix, 0), 15);
      int pos = iyc * 16 + ixc;
      half8 bh = *(const half8*)(sm + pos * 72 + kc * 32 + quad * 8);
      half8 bl = *(const half8*)(sm + 18432 + pos * 72 + kc * 32 + quad * 8);
      if (oob) { bh = hzero(); bl = hzero(); }
#pragma unroll
      for (int mt = 0; mt < 2; mt++) {
        acch[nt][mt] = MFMA_F16(ah[mt], bh, acch[nt][mt]);
        accl[nt][mt] = MFMA_F16(al[mt], bh, accl[nt][mt]);
        accl[nt][mt] = MFMA_F16(ah[mt], bl, accl[nt][mt]);
      }
    }
  }

  // kc-combine via LDS C [co 32][260] (33280 B, reuses sm)
  __syncthreads();
  float* C = (float*)sm;
  if (kc == 0) {
#pragma unroll
    for (int nt = 0; nt < 4; nt++) {
      int pos = (qh * 4 + (nt >> 1) * 2 + wy) * 16 + (nt & 1) * 8 + x_l;
#pragma unroll
      for (int mt = 0; mt < 2; mt++)
#pragma unroll
        for (int r = 0; r < 4; r++)
          C[(mt * 16 + quad * 4 + r) * 260 + pos] = acch[nt][mt][r] + LO_SCALE * accl[nt][mt][r];
    }
  }
  __syncthreads();
  if (kc == 1) {
#pragma unroll
    for (int nt = 0; nt < 4; nt++) {
      int pos = (qh * 4 + (nt >> 1) * 2 + wy) * 16 + (nt & 1) * 8 + x_l;
#pragma unroll
      for (int mt = 0; mt < 2; mt++)
#pragma unroll
        for (int r = 0; r < 4; r++) {
          int a = (mt * 16 + quad * 4 + r) * 260 + pos;
          C[a] += acch[nt][mt][r] + LO_SCALE * accl[nt][mt][r];
        }
    }
  }
  __syncthreads();

  float* op = P0 + tg * 2097152 + (b * 128 + cg * 32) * 256;
  for (int m = tid; m < 8192; m += 512) {
    int co = m >> 8, pos = m & 255;
    op[co * 256 + pos] = C[co * 260 + pos];
  }
}

// ---------------- K2b: conv0 combine: pool/argmax + s1 update + u split-write ----------------
// grid (64 b, 32), 256 thr: idx in [0,8192) = co(128) x win(64).
__global__ __launch_bounds__(256) void k_c0comb(
    const float* __restrict__ P0, const float* __restrict__ s1old,
    const float* __restrict__ s0old, const float* __restrict__ fcw,
    float* __restrict__ s1new, _Float16* __restrict__ uh, _Float16* __restrict__ ul) {
  int b = blockIdx.x;
  int idx = blockIdx.y * 256 + threadIdx.x;
  int co = idx >> 6, win = idx & 63;
  int ph = win >> 3, pw = win & 7;
  int pos0 = ph * 32 + pw * 2;
  const float* pa = P0 + b * 32768 + co * 256;
  const float* pb = pa + 2097152;
  float v0 = pa[pos0]      + pb[pos0];
  float v1 = pa[pos0 + 1]  + pb[pos0 + 1];
  float v2 = pa[pos0 + 16] + pb[pos0 + 16];
  float v3 = pa[pos0 + 17] + pb[pos0 + 17];
  float m0 = v0; int id = 0;
  if (v1 > m0) { m0 = v1; id = 1; }
  if (v2 > m0) { m0 = v2; id = 2; }
  if (v3 > m0) { m0 = v3; id = 3; }
  int j = co * 64 + ph * 8 + pw;
  float a = m0;
#pragma unroll
  for (int k = 0; k < 10; k++) a += s0old[b * 10 + k] * fcw[k * 8192 + j];
  float sv = s1old[b * 8192 + j];
  s1new[b * 8192 + j] = rho_(a);
  _Float16 hh, hl; split2(sv, hh, hl);
  int bu = (b * 256 + pos0) * 128 + co;
  _Float16 z = (_Float16)0.f;
  uh[bu]        = (id == 0) ? hh : z;
  ul[bu]        = (id == 0) ? hl : z;
  uh[bu + 128]  = (id == 1) ? hh : z;
  ul[bu + 128]  = (id == 1) ? hl : z;
  uh[bu + 2048] = (id == 2) ? hh : z;
  ul[bu + 2048] = (id == 2) ? hl : z;
  uh[bu + 2176] = (id == 3) ? hh : z;
  ul[bu + 2176] = (id == 3) ? hl : z;
}

// ---------------- K3: convT GEMM (cp-half x o-half x tap-group partial) ----------------
// up[o,y,x] = sum_{cp,ky,kx} W0[cp][o][ky][kx] * u[cp, y+2-ky, x+2-kx]
// grid (64 b, 2 ks, 2 oh, 2 tg) = 512 blocks, 512 thr = 8 waves = kc(2) x qh(4).
// Wave: m=2 mt (oh's 32 o), n=4 nt, K=32 (kc of ks's 64 cp). P1[(tg*2+ks)][b][o][pos].
__global__ __launch_bounds__(512, 4) void k_convTg(
    const _Float16* __restrict__ uh, const _Float16* __restrict__ ul,
    const _Float16* __restrict__ wA1h, const _Float16* __restrict__ wA1l,
    float* __restrict__ P1) {
  __shared__ __align__(16) _Float16 sm[36864];
  int b = blockIdx.x, tid = threadIdx.x;
  int ks = blockIdx.y & 1;
  int oh = blockIdx.y >> 1;
  int tg = blockIdx.z;

  for (int i = tid; i < 8192; i += 512) {
    int pos = i >> 5, c2 = i & 31;
    int off = b * 32768 + pos * 128 + ks * 64 + c2 * 2;
    *(unsigned*)(sm + pos * 72 + c2 * 2) = *(const unsigned*)(uh + off);
    *(unsigned*)(sm + 18432 + pos * 72 + c2 * 2) = *(const unsigned*)(ul + off);
  }
  __syncthreads();

  int lane = tid & 63, w = tid >> 6;
  int kc = w & 1, qh = w >> 1;
  int l16 = lane & 15, quad = lane >> 4;
  int wy = (l16 >> 1) & 1;
  int x_l = ((l16 >> 2) << 1) + (l16 & 1);

  f32x4 acch[4][2], accl[4][2];
#pragma unroll
  for (int nt = 0; nt < 4; nt++)
#pragma unroll
    for (int mt = 0; mt < 2; mt++) {
      f32x4 z; z[0] = 0.f; z[1] = 0.f; z[2] = 0.f; z[3] = 0.f;
      acch[nt][mt] = z; accl[nt][mt] = z;
    }

  int tap0 = tg * 13, tap1 = tg ? 25 : 13;
  for (int tap = tap0; tap < tap1; tap++) {
    int ky = tap / 5, kx = tap % 5;
    int c = ks * 2 + kc;
    const _Float16* ap  = wA1h + ((tap * 4 + c) * 64 + oh * 32 + l16) * 32 + quad * 8;
    const _Float16* alp = wA1l + ((tap * 4 + c) * 64 + oh * 32 + l16) * 32 + quad * 8;
    half8 ah[2], al[2];
#pragma unroll
    for (int mt = 0; mt < 2; mt++) {
      ah[mt] = *(const half8*)(ap + mt * 512);
      al[mt] = *(const half8*)(alp + mt * 512);
    }
#pragma unroll
    for (int nt = 0; nt < 4; nt++) {
      int y = qh * 4 + (nt >> 1) * 2 + wy;
      int x = (nt & 1) * 8 + x_l;
      int iy = y + 2 - ky, ix = x + 2 - kx;
      bool oob = ((unsigned)iy > 15u) || ((unsigned)ix > 15u);
      int iyc = min(max(iy, 0), 15), ixc = min(max(ix, 0), 15);
      int pos = iyc * 16 + ixc;
      half8 bh = *(const half8*)(sm + pos * 72 + kc * 32 + quad * 8);
      half8 bl = *(const half8*)(sm + 18432 + pos * 72 + kc * 32 + quad * 8);
      if (oob) { bh = hzero(); bl = hzero(); }
#pragma unroll
      for (int mt = 0; mt < 2; mt++) {
        acch[nt][mt] = MFMA_F16(ah[mt], bh, acch[nt][mt]);
        accl[nt][mt] = MFMA_F16(al[mt], bh, accl[nt][mt]);
        accl[nt][mt] = MFMA_F16(ah[mt], bl, accl[nt][mt]);
      }
    }
  }

  __syncthreads();
  float* C = (float*)sm;   // [o 32][260]
  if (kc == 0) {
#pragma unroll
    for (int nt = 0; nt < 4; nt++) {
      int pos = (qh * 4 + (nt >> 1) * 2 + wy) * 16 + (nt & 1) * 8 + x_l;
#pragma unroll
      for (int mt = 0; mt < 2; mt++)
#pragma unroll
        for (int r = 0; r < 4; r++)
          C[(mt * 16 + quad * 4 + r) * 260 + pos] = acch[nt][mt][r] + LO_SCALE * accl[nt][mt][r];
    }
  }
  __syncthreads();
  if (kc == 1) {
#pragma unroll
    for (int nt = 0; nt < 4; nt++) {
      int pos = (qh * 4 + (nt >> 1) * 2 + wy) * 16 + (nt & 1) * 8 + x_l;
#pragma unroll
      for (int mt = 0; mt < 2; mt++)
#pragma unroll
        for (int r = 0; r < 4; r++) {
          int a = (mt * 16 + quad * 4 + r) * 260 + pos;
          C[a] += acch[nt][mt][r] + LO_SCALE * accl[nt][mt][r];
        }
    }
  }
  __syncthreads();

  float* op = P1 + (tg * 2 + ks) * 1048576 + (b * 64 + oh * 32) * 256;
  for (int m = tid; m < 8192; m += 512) {
    int o = m >> 8, pos = m & 255;
    op[o * 256 + pos] = C[o * 260 + pos];
  }
}

// ---------------- K3b: s2 = rho(p2 + P1[0]+P1[1]+P1[2]+P1[3]) ----------------
__global__ __launch_bounds__(256) void k_cTcomb(
    const float* __restrict__ p2, const float* __restrict__ P1,
    float* __restrict__ s2new) {
  int i = blockIdx.x * 256 + threadIdx.x;   // over 262144 float4s
  float4 p = ((const float4*)p2)[i];
  float4 a0 = ((const float4*)P1)[i];
  float4 a1 = ((const float4*)(P1 + 1048576))[i];
  float4 a2 = ((const float4*)(P1 + 2097152))[i];
  float4 a3 = ((const float4*)(P1 + 3145728))[i];
  float4 o;
  o.x = rho_(p.x + a0.x + a1.x + a2.x + a3.x);
  o.y = rho_(p.y + a0.y + a1.y + a2.y + a3.y);
  o.z = rho_(p.z + a0.z + a1.z + a2.z + a3.z);
  o.w = rho_(p.w + a0.w + a1.w + a2.w + a3.w);
  ((float4*)s2new)[i] = o;
}

// ---------------- K5: s0_new = rho(s1_old_flat @ fc_w^T + fc_b) ----------------
__global__ __launch_bounds__(256) void k_s0fc(
    const float* __restrict__ s1old, const float* __restrict__ fcw,
    const float* __restrict__ fcb, float* __restrict__ s0new) {
  __shared__ float red[10][256];
  int b = blockIdx.x, tid = threadIdx.x;
  float acc[10];
#pragma unroll
  for (int o = 0; o < 10; o++) acc[o] = 0.f;
  const float* sb = s1old + b * 8192;
  for (int i = tid; i < 8192; i += 256) {
    float v = sb[i];
#pragma unroll
    for (int o = 0; o < 10; o++) acc[o] += v * fcw[o * 8192 + i];
  }
#pragma unroll
  for (int o = 0; o < 10; o++) red[o][tid] = acc[o];
  __syncthreads();
  for (int s = 128; s > 0; s >>= 1) {
    if (tid < s) {
#pragma unroll
      for (int o = 0; o < 10; o++) red[o][tid] += red[o][tid + s];
    }
    __syncthreads();
  }
  if (tid < 10) s0new[b * 10 + tid] = rho_(red[tid][0] + fcb[tid]);
}

extern "C" void kernel_launch(void* const* d_in, const int* in_sizes, int n_in,
                              void* d_out, int out_size, void* d_ws, size_t ws_size,
                              hipStream_t stream) {
  const float* data   = (const float*)d_in[0];
  const float* s0init = (const float*)d_in[1];   // zeros
  const float* s1init = (const float*)d_in[2];   // zeros
  const float* s2init = (const float*)d_in[3];   // zeros
  const float* conv0w = (const float*)d_in[4];
  const float* conv0b = (const float*)d_in[5];
  const float* conv1w = (const float*)d_in[6];
  const float* conv1b = (const float*)d_in[7];
  const float* fcw    = (const float*)d_in[8];
  const float* fcb    = (const float*)d_in[9];

  // workspace (~37.4 MB)
  float* p = (float*)d_ws;
  float* s0buf[2] = {p, p + 640};            p += 1280;
  float* s1ws = p;                           p += 524288;
  float* s2ws = p;                           p += 1048576;
  float* p2 = p;                             p += 1048576;
  float* P  = p;                             p += 4194304;   // shared: conv0 2x2.1M / convT 4x1.05M
  _Float16* hq = (_Float16*)p;
  _Float16* uh   = hq;                       hq += 2097152;  // [b][pos 256][cp 128]
  _Float16* ul   = hq;                       hq += 2097152;
  _Float16* wA0h = hq;                       hq += 204800;
  _Float16* wA0l = hq;                       hq += 204800;
  _Float16* wA1h = hq;                       hq += 204800;
  _Float16* wA1l = hq;                       hq += 204800;

  k_wprep<<<800, 256, 0, stream>>>(conv0w, wA0h, wA0l, wA1h, wA1l);
  k_p2<<<dim3(64, 4), 256, 0, stream>>>(data, conv1w, conv1b, p2);

  const float* s0o = s0init;
  const float* s1o = s1init;
  const float* s2o = s2init;
  float* outp = (float*)d_out;

  for (int t = 0; t < 10; t++) {
    float* s0w = s0buf[t & 1];

    // conv0 GEMM partials from s2_old
    k_conv0g<<<dim3(64, 4, 2), 512, 0, stream>>>(s2o, wA0h, wA0l, conv0b, P);
    // s0_new = rho(fc(s1_old))  (reads s1_old before c0comb overwrites it)
    k_s0fc<<<64, 256, 0, stream>>>(s1o, fcw, fcb, s0w);
    // combine: pool/argmax; s1 = rho(p1 + fc^T(s0_old)); u = split(unpool(s1_old, idx))
    k_c0comb<<<dim3(64, 32), 256, 0, stream>>>(P, s1o, s0o, fcw, s1ws, uh, ul);
    // convT GEMM partials + combine: s2 = rho(p2 + sum partials)
    k_convTg<<<dim3(64, 4, 2), 512, 0, stream>>>(uh, ul, wA1h, wA1l, P);
    k_cTcomb<<<1024, 256, 0, stream>>>(p2, P, s2ws);

    s0o = s0w; s1o = s1ws; s2o = s2ws;

    if (t == 6) {   // PRED_T snapshot (post-update states)
      hipMemcpyAsync(outp + 1573504, s0w,  640 * sizeof(float),     hipMemcpyDeviceToDevice, stream);
      hipMemcpyAsync(outp + 1574144, s1ws, 524288 * sizeof(float),  hipMemcpyDeviceToDevice, stream);
      hipMemcpyAsync(outp + 2098432, s2ws, 1048576 * sizeof(float), hipMemcpyDeviceToDevice, stream);
    }
  }

  // final states
  hipMemcpyAsync(outp + 0,      s0o, 640 * sizeof(float),     hipMemcpyDeviceToDevice, stream);
  hipMemcpyAsync(outp + 640,    s1o, 524288 * sizeof(float),  hipMemcpyDeviceToDevice, stream);
  hipMemcpyAsync(outp + 524928, s2o, 1048576 * sizeof(float), hipMemcpyDeviceToDevice, stream);
}

// Round 12
// 953.649 us; speedup vs baseline: 1.5188x; 1.0703x over previous
//
#include <hip/hip_runtime.h>

// convEP: 10-step EP relaxation, MFMA fp16 2-way-split convs (fp32-equivalent).
//   s0' = rho(fc(s1));  s1' = rho(pool(conv0(s2)) + fc^T(s0));  s2' = rho(p2 + convT(unpool(s1, idx1)))
// fp32 x = xh + 2^-12*xl' (fp16 planes, lo pre-scaled 2^12 to stay fp16-normal).
// x*y ~= xh*yh + 2^-12*(xh*yl' + xl'*yh); acc_hi/acc_lo separate, combined at epilogue.
// MFMA 16x16x32_f16: A[m=l16][k=quad*8+j], B[k=quad*8+j][n=l16], C/D: col=l16, row=quad*4+reg.
// R12: pipeline fusion — conv0 block owns full conv output (25 taps, no tg split):
//  * staging computes s2 = rho(p2 + sum P1 partials) on the fly (cTcomb fused; bit-identical order)
//  * epilogue does pool/argmax + s1 update + u split-write (c0comb fused)
//  * k_cTcomb only at t=6/t=9, writing straight into d_out. 3 kernels/step (was 5).

typedef _Float16 half8 __attribute__((ext_vector_type(8)));
typedef float f32x4 __attribute__((ext_vector_type(4)));
#define MFMA_F16(A, B, C) __builtin_amdgcn_mfma_f32_16x16x32_f16((A), (B), (C), 0, 0, 0)
#define LO_SCALE 2.44140625e-4f   // 2^-12

static __device__ __forceinline__ float rho_(float x) {
  return fminf(fmaxf(x, 0.0f), 1.0f);
}
static __device__ __forceinline__ void split2(float v, _Float16& h, _Float16& l) {
  if (fabsf(v) < 6.1035156e-5f) {
    h = (_Float16)0.f;
    l = (_Float16)(v * 4096.f);
  } else {
    h = (_Float16)v;
    l = (_Float16)((v - (float)h) * 4096.f);
  }
}
static __device__ __forceinline__ half8 hzero() {
  half8 z;
#pragma unroll
  for (int j = 0; j < 8; j++) z[j] = (_Float16)0.f;
  return z;
}

// ---------------- K0: one-time weight split+transpose ----------------
// wA0[((tap*2+kc)*128 + co)*32 + cik] = conv0w[co][kc*32+cik][tap]
// wA1[((tap*4+c )*64  + o )*32 + cpk] = conv0w[(c*32+cpk)][o][tap]
__global__ __launch_bounds__(256) void k_wprep(
    const float* __restrict__ w0,
    _Float16* __restrict__ wA0h, _Float16* __restrict__ wA0l,
    _Float16* __restrict__ wA1h, _Float16* __restrict__ wA1l) {
  int i = blockIdx.x * 256 + threadIdx.x;
  if (i >= 204800) return;
  {
    int cik = i & 31, t1 = i >> 5;
    int co = t1 & 127, t2 = t1 >> 7;
    int ck = t2 & 1, tap = t2 >> 1;
    float v = w0[(co * 64 + ck * 32 + cik) * 25 + tap];
    _Float16 h, l; split2(v, h, l);
    wA0h[i] = h; wA0l[i] = l;
  }
  {
    int cpk = i & 31, t1 = i >> 5;
    int o = t1 & 63, t2 = t1 >> 6;
    int c = t2 & 3, tap = t2 >> 2;
    float v = w0[((c * 32 + cpk) * 64 + o) * 25 + tap];
    _Float16 h, l; split2(v, h, l);
    wA1h[i] = h; wA1l[i] = l;
  }
}

// ---------------- K1: p2 = maxpool2x2(conv2d(data, conv1_w) + conv1_b) (once, fp32) ----------------
__global__ __launch_bounds__(256) void k_p2(
    const float* __restrict__ data, const float* __restrict__ w,
    const float* __restrict__ bias, float* __restrict__ p2) {
  __shared__ float ld[3][36][36];
  __shared__ float lw[16][80];
  __shared__ float lb[16];
  int b = blockIdx.x, cg = blockIdx.y, tid = threadIdx.x;
  for (int i = tid; i < 3 * 36 * 36; i += 256) {
    int ci = i / 1296, rem = i % 1296, y = rem / 36, x = rem % 36;
    int gy = y - 2, gx = x - 2;
    float v = 0.f;
    if (gy >= 0 && gy < 32 && gx >= 0 && gx < 32)
      v = data[(b * 3 + ci) * 1024 + gy * 32 + gx];
    ld[ci][y][x] = v;
  }
  for (int i = tid; i < 16 * 75; i += 256) {
    int co = i / 75, k = i % 75;
    lw[co][k] = w[(cg * 16 + co) * 75 + k];
  }
  if (tid < 16) lb[tid] = bias[cg * 16 + tid];
  __syncthreads();
  int ph = tid >> 4, pw = tid & 15;
  int ry = 2 * ph, rx = 2 * pw;
  for (int co = 0; co < 16; co++) {
    float bv = lb[co];
    float a00 = bv, a01 = bv, a10 = bv, a11 = bv;
    for (int ci = 0; ci < 3; ci++) {
#pragma unroll
      for (int ky = 0; ky < 5; ky++) {
#pragma unroll
        for (int kx = 0; kx < 5; kx++) {
          float wv = lw[co][(ci * 5 + ky) * 5 + kx];
          a00 += wv * ld[ci][ry + ky][rx + kx];
          a01 += wv * ld[ci][ry + ky][rx + kx + 1];
          a10 += wv * ld[ci][ry + ky + 1][rx + kx];
          a11 += wv * ld[ci][ry + ky + 1][rx + kx + 1];
        }
      }
    }
    float m = fmaxf(fmaxf(a00, a01), fmaxf(a10, a11));
    p2[((b * 64 + cg * 16 + co) * 16 + ph) * 16 + pw] = m;
  }
}

// ---------------- K2: conv0 FULL (GEMM 25 taps + pool/argmax + s1 update + u write) ----------------
// grid (64 b, 4 cg) = 256 blocks, 512 thr = 8 waves = kc(2) x qh(4).
// Wave: m=2 mt (cg's 32 co), n=4 nt, K=32 (kc). Input staged as either s2init (t=0) or
// rho(p2 + P1[0..3]) computed on the fly (t>0; exact cTcomb add order). kc-combine in LDS,
// then epilogue: pool/argmax -> s1_new = rho(m + fc^T(s0_old)); u = split2(unpool(s1_old, idx)).
__global__ __launch_bounds__(512, 2) void k_conv0F(
    const float* __restrict__ s2init, const float* __restrict__ p2,
    const float* __restrict__ P1, int fused,
    const _Float16* __restrict__ wA0h, const _Float16* __restrict__ wA0l,
    const float* __restrict__ b0,
    const float* __restrict__ s1old, const float* __restrict__ s0old,
    const float* __restrict__ fcw, float* __restrict__ s1new,
    _Float16* __restrict__ uh, _Float16* __restrict__ ul) {
  __shared__ __align__(16) _Float16 sm[36864];   // 2 planes x [pos 256][ci 64+8] = 73728 B
  int b = blockIdx.x, cg = blockIdx.y, tid = threadIdx.x;

  // stage input (s2_t): fused mode computes rho(p2 + sum of 4 P1 partials), same order as cTcomb
  for (int i = tid; i < 16384; i += 512) {
    int ci = i >> 8, pos = i & 255;
    int gi = b * 16384 + i;
    float v;
    if (fused) {
      v = rho_(p2[gi] + P1[gi] + P1[gi + 1048576] + P1[gi + 2097152] + P1[gi + 3145728]);
    } else {
      v = s2init[gi];
    }
    _Float16 h, l; split2(v, h, l);
    sm[pos * 72 + ci] = h;
    sm[18432 + pos * 72 + ci] = l;
  }
  __syncthreads();

  int lane = tid & 63, w = tid >> 6;
  int kc = w & 1, qh = w >> 1;
  int l16 = lane & 15, quad = lane >> 4;
  int wy = (l16 >> 1) & 1;
  int x_l = ((l16 >> 2) << 1) + (l16 & 1);

  f32x4 acch[4][2], accl[4][2];   // [nt][mt]
#pragma unroll
  for (int nt = 0; nt < 4; nt++)
#pragma unroll
    for (int mt = 0; mt < 2; mt++) {
      f32x4 z; z[0] = 0.f; z[1] = 0.f; z[2] = 0.f; z[3] = 0.f;
      accl[nt][mt] = z;
      if (kc == 0) {   // bias enters exactly once (kc=0 partial)
        int cb = cg * 32 + mt * 16 + quad * 4;
        f32x4 bi; bi[0] = b0[cb]; bi[1] = b0[cb + 1]; bi[2] = b0[cb + 2]; bi[3] = b0[cb + 3];
        acch[nt][mt] = bi;
      } else {
        acch[nt][mt] = z;
      }
    }

  for (int tap = 0; tap < 25; tap++) {
    int ky = tap / 5, kx = tap % 5;
    const _Float16* ap  = wA0h + ((tap * 2 + kc) * 128 + cg * 32 + l16) * 32 + quad * 8;
    const _Float16* alp = wA0l + ((tap * 2 + kc) * 128 + cg * 32 + l16) * 32 + quad * 8;
    half8 ah[2], al[2];
#pragma unroll
    for (int mt = 0; mt < 2; mt++) {
      ah[mt] = *(const half8*)(ap + mt * 512);
      al[mt] = *(const half8*)(alp + mt * 512);
    }
#pragma unroll
    for (int nt = 0; nt < 4; nt++) {
      int y = qh * 4 + (nt >> 1) * 2 + wy;
      int x = (nt & 1) * 8 + x_l;
      int iy = y + ky - 2, ix = x + kx - 2;
      bool oob = ((unsigned)iy > 15u) || ((unsigned)ix > 15u);
      int iyc = min(max(iy, 0), 15), ixc = min(max(ix, 0), 15);
      int pos = iyc * 16 + ixc;
      half8 bh = *(const half8*)(sm + pos * 72 + kc * 32 + quad * 8);
      half8 bl = *(const half8*)(sm + 18432 + pos * 72 + kc * 32 + quad * 8);
      if (oob) { bh = hzero(); bl = hzero(); }
#pragma unroll
      for (int mt = 0; mt < 2; mt++) {
        acch[nt][mt] = MFMA_F16(ah[mt], bh, acch[nt][mt]);
        accl[nt][mt] = MFMA_F16(al[mt], bh, accl[nt][mt]);
        accl[nt][mt] = MFMA_F16(ah[mt], bl, accl[nt][mt]);
      }
    }
  }

  // kc-combine via LDS C [co 32][260] (33280 B, reuses sm)
  __syncthreads();
  float* C = (float*)sm;
  if (kc == 0) {
#pragma unroll
    for (int nt = 0; nt < 4; nt++) {
      int pos = (qh * 4 + (nt >> 1) * 2 + wy) * 16 + (nt & 1) * 8 + x_l;
#pragma unroll
      for (int mt = 0; mt < 2; mt++)
#pragma unroll
        for (int r = 0; r < 4; r++)
          C[(mt * 16 + quad * 4 + r) * 260 + pos] = acch[nt][mt][r] + LO_SCALE * accl[nt][mt][r];
    }
  }
  __syncthreads();
  if (kc == 1) {
#pragma unroll
    for (int nt = 0; nt < 4; nt++) {
      int pos = (qh * 4 + (nt >> 1) * 2 + wy) * 16 + (nt & 1) * 8 + x_l;
#pragma unroll
      for (int mt = 0; mt < 2; mt++)
#pragma unroll
        for (int r = 0; r < 4; r++) {
          int a = (mt * 16 + quad * 4 + r) * 260 + pos;
          C[a] += acch[nt][mt][r] + LO_SCALE * accl[nt][mt][r];
        }
    }
  }
  __syncthreads();

  // epilogue: pool/argmax + fused s1 update + u split-write (cg's 32 co x 64 windows)
  for (int it = 0; it < 4; it++) {
    int idx = it * 512 + tid;          // 2048 = 32 co x 64 windows
    int co = idx >> 6, win = idx & 63;
    int ph = win >> 3, pw = win & 7;
    int pos0 = ph * 32 + pw * 2;
    float v0 = C[co * 260 + pos0];
    float v1 = C[co * 260 + pos0 + 1];
    float v2 = C[co * 260 + pos0 + 16];
    float v3 = C[co * 260 + pos0 + 17];
    float m0 = v0; int id = 0;
    if (v1 > m0) { m0 = v1; id = 1; }
    if (v2 > m0) { m0 = v2; id = 2; }
    if (v3 > m0) { m0 = v3; id = 3; }
    int co_g = cg * 32 + co;
    int j = co_g * 64 + ph * 8 + pw;
    float a = m0;
#pragma unroll
    for (int k = 0; k < 10; k++) a += s0old[b * 10 + k] * fcw[k * 8192 + j];
    float sv = s1old[b * 8192 + j];
    s1new[b * 8192 + j] = rho_(a);
    _Float16 hh, hl; split2(sv, hh, hl);
    int bu = (b * 256 + pos0) * 128 + co_g;
    _Float16 z = (_Float16)0.f;
    uh[bu]        = (id == 0) ? hh : z;
    ul[bu]        = (id == 0) ? hl : z;
    uh[bu + 128]  = (id == 1) ? hh : z;
    ul[bu + 128]  = (id == 1) ? hl : z;
    uh[bu + 2048] = (id == 2) ? hh : z;
    ul[bu + 2048] = (id == 2) ? hl : z;
    uh[bu + 2176] = (id == 3) ? hh : z;
    ul[bu + 2176] = (id == 3) ? hl : z;
  }
}

// ---------------- K3: convT GEMM (cp-half x o-half x tap-group partial) — unchanged R11 ----------------
__global__ __launch_bounds__(512, 4) void k_convTg(
    const _Float16* __restrict__ uh, const _Float16* __restrict__ ul,
    const _Float16* __restrict__ wA1h, const _Float16* __restrict__ wA1l,
    float* __restrict__ P1) {
  __shared__ __align__(16) _Float16 sm[36864];
  int b = blockIdx.x, tid = threadIdx.x;
  int ks = blockIdx.y & 1;
  int oh = blockIdx.y >> 1;
  int tg = blockIdx.z;

  for (int i = tid; i < 8192; i += 512) {
    int pos = i >> 5, c2 = i & 31;
    int off = b * 32768 + pos * 128 + ks * 64 + c2 * 2;
    *(unsigned*)(sm + pos * 72 + c2 * 2) = *(const unsigned*)(uh + off);
    *(unsigned*)(sm + 18432 + pos * 72 + c2 * 2) = *(const unsigned*)(ul + off);
  }
  __syncthreads();

  int lane = tid & 63, w = tid >> 6;
  int kc = w & 1, qh = w >> 1;
  int l16 = lane & 15, quad = lane >> 4;
  int wy = (l16 >> 1) & 1;
  int x_l = ((l16 >> 2) << 1) + (l16 & 1);

  f32x4 acch[4][2], accl[4][2];
#pragma unroll
  for (int nt = 0; nt < 4; nt++)
#pragma unroll
    for (int mt = 0; mt < 2; mt++) {
      f32x4 z; z[0] = 0.f; z[1] = 0.f; z[2] = 0.f; z[3] = 0.f;
      acch[nt][mt] = z; accl[nt][mt] = z;
    }

  int tap0 = tg * 13, tap1 = tg ? 25 : 13;
  for (int tap = tap0; tap < tap1; tap++) {
    int ky = tap / 5, kx = tap % 5;
    int c = ks * 2 + kc;
    const _Float16* ap  = wA1h + ((tap * 4 + c) * 64 + oh * 32 + l16) * 32 + quad * 8;
    const _Float16* alp = wA1l + ((tap * 4 + c) * 64 + oh * 32 + l16) * 32 + quad * 8;
    half8 ah[2], al[2];
#pragma unroll
    for (int mt = 0; mt < 2; mt++) {
      ah[mt] = *(const half8*)(ap + mt * 512);
      al[mt] = *(const half8*)(alp + mt * 512);
    }
#pragma unroll
    for (int nt = 0; nt < 4; nt++) {
      int y = qh * 4 + (nt >> 1) * 2 + wy;
      int x = (nt & 1) * 8 + x_l;
      int iy = y + 2 - ky, ix = x + 2 - kx;
      bool oob = ((unsigned)iy > 15u) || ((unsigned)ix > 15u);
      int iyc = min(max(iy, 0), 15), ixc = min(max(ix, 0), 15);
      int pos = iyc * 16 + ixc;
      half8 bh = *(const half8*)(sm + pos * 72 + kc * 32 + quad * 8);
      half8 bl = *(const half8*)(sm + 18432 + pos * 72 + kc * 32 + quad * 8);
      if (oob) { bh = hzero(); bl = hzero(); }
#pragma unroll
      for (int mt = 0; mt < 2; mt++) {
        acch[nt][mt] = MFMA_F16(ah[mt], bh, acch[nt][mt]);
        accl[nt][mt] = MFMA_F16(al[mt], bh, accl[nt][mt]);
        accl[nt][mt] = MFMA_F16(ah[mt], bl, accl[nt][mt]);
      }
    }
  }

  __syncthreads();
  float* C = (float*)sm;   // [o 32][260]
  if (kc == 0) {
#pragma unroll
    for (int nt = 0; nt < 4; nt++) {
      int pos = (qh * 4 + (nt >> 1) * 2 + wy) * 16 + (nt & 1) * 8 + x_l;
#pragma unroll
      for (int mt = 0; mt < 2; mt++)
#pragma unroll
        for (int r = 0; r < 4; r++)
          C[(mt * 16 + quad * 4 + r) * 260 + pos] = acch[nt][mt][r] + LO_SCALE * accl[nt][mt][r];
    }
  }
  __syncthreads();
  if (kc == 1) {
#pragma unroll
    for (int nt = 0; nt < 4; nt++) {
      int pos = (qh * 4 + (nt >> 1) * 2 + wy) * 16 + (nt & 1) * 8 + x_l;
#pragma unroll
      for (int mt = 0; mt < 2; mt++)
#pragma unroll
        for (int r = 0; r < 4; r++) {
          int a = (mt * 16 + quad * 4 + r) * 260 + pos;
          C[a] += acch[nt][mt][r] + LO_SCALE * accl[nt][mt][r];
        }
    }
  }
  __syncthreads();

  float* op = P1 + (tg * 2 + ks) * 1048576 + (b * 64 + oh * 32) * 256;
  for (int m = tid; m < 8192; m += 512) {
    int o = m >> 8, pos = m & 255;
    op[o * 256 + pos] = C[o * 260 + pos];
  }
}

// ---------------- K3b: out = rho(p2 + P1[0..3])  (only at t=6 snapshot and t=9 final) ----------------
__global__ __launch_bounds__(256) void k_cTcomb(
    const float* __restrict__ p2, const float* __restrict__ P1,
    float* __restrict__ outv) {
  int i = blockIdx.x * 256 + threadIdx.x;   // over 262144 float4s
  float4 p = ((const float4*)p2)[i];
  float4 a0 = ((const float4*)P1)[i];
  float4 a1 = ((const float4*)(P1 + 1048576))[i];
  float4 a2 = ((const float4*)(P1 + 2097152))[i];
  float4 a3 = ((const float4*)(P1 + 3145728))[i];
  float4 o;
  o.x = rho_(p.x + a0.x + a1.x + a2.x + a3.x);
  o.y = rho_(p.y + a0.y + a1.y + a2.y + a3.y);
  o.z = rho_(p.z + a0.z + a1.z + a2.z + a3.z);
  o.w = rho_(p.w + a0.w + a1.w + a2.w + a3.w);
  ((float4*)outv)[i] = o;
}

// ---------------- K5: s0_new = rho(s1_old_flat @ fc_w^T + fc_b) ----------------
__global__ __launch_bounds__(256) void k_s0fc(
    const float* __restrict__ s1old, const float* __restrict__ fcw,
    const float* __restrict__ fcb, float* __restrict__ s0new) {
  __shared__ float red[10][256];
  int b = blockIdx.x, tid = threadIdx.x;
  float acc[10];
#pragma unroll
  for (int o = 0; o < 10; o++) acc[o] = 0.f;
  const float* sb = s1old + b * 8192;
  for (int i = tid; i < 8192; i += 256) {
    float v = sb[i];
#pragma unroll
    for (int o = 0; o < 10; o++) acc[o] += v * fcw[o * 8192 + i];
  }
#pragma unroll
  for (int o = 0; o < 10; o++) red[o][tid] = acc[o];
  __syncthreads();
  for (int s = 128; s > 0; s >>= 1) {
    if (tid < s) {
#pragma unroll
      for (int o = 0; o < 10; o++) red[o][tid] += red[o][tid + s];
    }
    __syncthreads();
  }
  if (tid < 10) s0new[b * 10 + tid] = rho_(red[tid][0] + fcb[tid]);
}

extern "C" void kernel_launch(void* const* d_in, const int* in_sizes, int n_in,
                              void* d_out, int out_size, void* d_ws, size_t ws_size,
                              hipStream_t stream) {
  const float* data   = (const float*)d_in[0];
  const float* s0init = (const float*)d_in[1];   // zeros
  const float* s1init = (const float*)d_in[2];   // zeros
  const float* s2init = (const float*)d_in[3];   // zeros (t=0 conv0 input)
  const float* conv0w = (const float*)d_in[4];
  const float* conv0b = (const float*)d_in[5];
  const float* conv1w = (const float*)d_in[6];
  const float* conv1b = (const float*)d_in[7];
  const float* fcw    = (const float*)d_in[8];
  const float* fcb    = (const float*)d_in[9];

  // workspace (~35 MB): no P0, no s2 buffer (s2 exists only inside conv0F / cTcomb-to-out)
  float* p = (float*)d_ws;
  float* s0buf[2] = {p, p + 640};            p += 1280;
  float* s1buf[2] = {p, p + 524288};         p += 1048576;
  float* p2 = p;                             p += 1048576;
  float* P1 = p;                             p += 4194304;   // 4 x 1M convT partials
  _Float16* hq = (_Float16*)p;
  _Float16* uh   = hq;                       hq += 2097152;  // [b][pos 256][cp 128]
  _Float16* ul   = hq;                       hq += 2097152;
  _Float16* wA0h = hq;                       hq += 204800;
  _Float16* wA0l = hq;                       hq += 204800;
  _Float16* wA1h = hq;                       hq += 204800;
  _Float16* wA1l = hq;                       hq += 204800;

  k_wprep<<<800, 256, 0, stream>>>(conv0w, wA0h, wA0l, wA1h, wA1l);
  k_p2<<<dim3(64, 4), 256, 0, stream>>>(data, conv1w, conv1b, p2);

  const float* s0o = s0init;
  const float* s1o = s1init;
  float* outp = (float*)d_out;

  for (int t = 0; t < 10; t++) {
    int nb = t & 1;
    float* s0w = s0buf[nb];
    float* s1w = s1buf[nb];

    // s0_new = rho(fc(s1_old))
    k_s0fc<<<64, 256, 0, stream>>>(s1o, fcw, fcb, s0w);
    // conv0(s2_t) [s2_t = rho(p2+sumP1) fused for t>0] + pool/argmax;
    // s1_new = rho(p1 + fc^T(s0_old)); u = split(unpool(s1_old, idx))
    k_conv0F<<<dim3(64, 4), 512, 0, stream>>>(s2init, p2, P1, (t > 0),
                                              wA0h, wA0l, conv0b,
                                              s1o, s0o, fcw, s1w, uh, ul);
    // convT partials (consumed by next step's conv0F staging, or cTcomb at t=6/9)
    k_convTg<<<dim3(64, 4, 2), 512, 0, stream>>>(uh, ul, wA1h, wA1l, P1);

    s0o = s0w; s1o = s1w;

    if (t == 6) {   // PRED_T snapshot (post-update states); s2_7 = rho(p2+sumP1) -> d_out directly
      hipMemcpyAsync(outp + 1573504, s0w, 640 * sizeof(float),    hipMemcpyDeviceToDevice, stream);
      hipMemcpyAsync(outp + 1574144, s1w, 524288 * sizeof(float), hipMemcpyDeviceToDevice, stream);
      k_cTcomb<<<1024, 256, 0, stream>>>(p2, P1, outp + 2098432);
    }
  }

  // final states: s0_10, s1_10 via copies; s2_10 materialized straight into d_out
  hipMemcpyAsync(outp + 0,   s0o, 640 * sizeof(float),    hipMemcpyDeviceToDevice, stream);
  hipMemcpyAsync(outp + 640, s1o, 524288 * sizeof(float), hipMemcpyDeviceToDevice, stream);
  k_cTcomb<<<1024, 256, 0, stream>>>(p2, P1, outp + 524928);
}

// Round 13
// 915.066 us; speedup vs baseline: 1.5828x; 1.0422x over previous
//
#include <hip/hip_runtime.h>

// convEP: 10-step EP relaxation, MFMA fp16 2-way-split convs (fp32-equivalent).
//   s0' = rho(fc(s1));  s1' = rho(pool(conv0(s2)) + fc^T(s0));  s2' = rho(p2 + convT(unpool(s1, idx1)))
// fp32 x = xh + 2^-12*xl' (fp16 planes, lo pre-scaled 2^12 to stay fp16-normal).
// x*y ~= xh*yh + 2^-12*(xh*yl' + xl'*yh); acc_hi/acc_lo separate, combined at epilogue.
// MFMA 16x16x32_f16: A[m=l16][k=quad*8+j], B[k=quad*8+j][n=l16], C/D: col=l16, row=quad*4+reg.
// R13: conv0F y-half position split -> grid 512, 55KB LDS slab (12 halo rows), 2 blocks/CU,
// 4 waves/SIMD (matches convTg's proven occupancy shape). Fused epilogue preserved
// (pool windows are whole within an 8-row half). Numerics bit-identical to R12.

typedef _Float16 half8 __attribute__((ext_vector_type(8)));
typedef float f32x4 __attribute__((ext_vector_type(4)));
#define MFMA_F16(A, B, C) __builtin_amdgcn_mfma_f32_16x16x32_f16((A), (B), (C), 0, 0, 0)
#define LO_SCALE 2.44140625e-4f   // 2^-12

static __device__ __forceinline__ float rho_(float x) {
  return fminf(fmaxf(x, 0.0f), 1.0f);
}
static __device__ __forceinline__ void split2(float v, _Float16& h, _Float16& l) {
  if (fabsf(v) < 6.1035156e-5f) {
    h = (_Float16)0.f;
    l = (_Float16)(v * 4096.f);
  } else {
    h = (_Float16)v;
    l = (_Float16)((v - (float)h) * 4096.f);
  }
}
static __device__ __forceinline__ half8 hzero() {
  half8 z;
#pragma unroll
  for (int j = 0; j < 8; j++) z[j] = (_Float16)0.f;
  return z;
}

// ---------------- K0: one-time weight split+transpose ----------------
// wA0[((tap*2+kc)*128 + co)*32 + cik] = conv0w[co][kc*32+cik][tap]
// wA1[((tap*4+c )*64  + o )*32 + cpk] = conv0w[(c*32+cpk)][o][tap]
__global__ __launch_bounds__(256) void k_wprep(
    const float* __restrict__ w0,
    _Float16* __restrict__ wA0h, _Float16* __restrict__ wA0l,
    _Float16* __restrict__ wA1h, _Float16* __restrict__ wA1l) {
  int i = blockIdx.x * 256 + threadIdx.x;
  if (i >= 204800) return;
  {
    int cik = i & 31, t1 = i >> 5;
    int co = t1 & 127, t2 = t1 >> 7;
    int ck = t2 & 1, tap = t2 >> 1;
    float v = w0[(co * 64 + ck * 32 + cik) * 25 + tap];
    _Float16 h, l; split2(v, h, l);
    wA0h[i] = h; wA0l[i] = l;
  }
  {
    int cpk = i & 31, t1 = i >> 5;
    int o = t1 & 63, t2 = t1 >> 6;
    int c = t2 & 3, tap = t2 >> 2;
    float v = w0[((c * 32 + cpk) * 64 + o) * 25 + tap];
    _Float16 h, l; split2(v, h, l);
    wA1h[i] = h; wA1l[i] = l;
  }
}

// ---------------- K1: p2 = maxpool2x2(conv2d(data, conv1_w) + conv1_b) (once, fp32) ----------------
__global__ __launch_bounds__(256) void k_p2(
    const float* __restrict__ data, const float* __restrict__ w,
    const float* __restrict__ bias, float* __restrict__ p2) {
  __shared__ float ld[3][36][36];
  __shared__ float lw[16][80];
  __shared__ float lb[16];
  int b = blockIdx.x, cg = blockIdx.y, tid = threadIdx.x;
  for (int i = tid; i < 3 * 36 * 36; i += 256) {
    int ci = i / 1296, rem = i % 1296, y = rem / 36, x = rem % 36;
    int gy = y - 2, gx = x - 2;
    float v = 0.f;
    if (gy >= 0 && gy < 32 && gx >= 0 && gx < 32)
      v = data[(b * 3 + ci) * 1024 + gy * 32 + gx];
    ld[ci][y][x] = v;
  }
  for (int i = tid; i < 16 * 75; i += 256) {
    int co = i / 75, k = i % 75;
    lw[co][k] = w[(cg * 16 + co) * 75 + k];
  }
  if (tid < 16) lb[tid] = bias[cg * 16 + tid];
  __syncthreads();
  int ph = tid >> 4, pw = tid & 15;
  int ry = 2 * ph, rx = 2 * pw;
  for (int co = 0; co < 16; co++) {
    float bv = lb[co];
    float a00 = bv, a01 = bv, a10 = bv, a11 = bv;
    for (int ci = 0; ci < 3; ci++) {
#pragma unroll
      for (int ky = 0; ky < 5; ky++) {
#pragma unroll
        for (int kx = 0; kx < 5; kx++) {
          float wv = lw[co][(ci * 5 + ky) * 5 + kx];
          a00 += wv * ld[ci][ry + ky][rx + kx];
          a01 += wv * ld[ci][ry + ky][rx + kx + 1];
          a10 += wv * ld[ci][ry + ky + 1][rx + kx];
          a11 += wv * ld[ci][ry + ky + 1][rx + kx + 1];
        }
      }
    }
    float m = fmaxf(fmaxf(a00, a01), fmaxf(a10, a11));
    p2[((b * 64 + cg * 16 + co) * 16 + ph) * 16 + pw] = m;
  }
}

// ---------------- K2: conv0 (y-half) + pool/argmax + s1 update + u write ----------------
// grid (64 b, 4 cg, 2 yh) = 512 blocks, 512 thr = 8 waves = kc(2) x qh(4).
// Wave: m=2 mt (cg's 32 co), n=2 nt (rows qh*2+nt of this y-half), K=32 (kc), all 25 taps.
// Staging: 12-row halo slab (rows yh*8-2..+9, y-pad baked in) of s2_t where
// s2_t = rho(p2 + sum 4 P1 partials) fused (t>0) or s2init (t=0). x-halo via clamp+hzero.
// kc-combine in LDS C [co 32][128+2]; epilogue = pool/argmax + s1 + u split-write.
__global__ __launch_bounds__(512, 4) void k_conv0F(
    const float* __restrict__ s2init, const float* __restrict__ p2,
    const float* __restrict__ P1, int fused,
    const _Float16* __restrict__ wA0h, const _Float16* __restrict__ wA0l,
    const float* __restrict__ b0,
    const float* __restrict__ s1old, const float* __restrict__ s0old,
    const float* __restrict__ fcw, float* __restrict__ s1new,
    _Float16* __restrict__ uh, _Float16* __restrict__ ul) {
  __shared__ __align__(16) _Float16 sm[27648];   // 2 planes x [pos 192][ci 64+8] = 55296 B
  int b = blockIdx.x, cg = blockIdx.y, yh = blockIdx.z, tid = threadIdx.x;

  // stage 12-row slab: pos = ly*16+lx (ly 0..11 -> gy = yh*8-2+ly), 64 ci
  for (int i = tid; i < 12288; i += 512) {
    int ci = i / 192;
    int pos = i - ci * 192;
    int ly = pos >> 4, lx = pos & 15;
    int gy = yh * 8 - 2 + ly;
    float v = 0.f;
    if (gy >= 0 && gy < 16) {
      int gi = b * 16384 + ci * 256 + gy * 16 + lx;
      if (fused) {
        v = rho_(p2[gi] + P1[gi] + P1[gi + 1048576] + P1[gi + 2097152] + P1[gi + 3145728]);
      } else {
        v = s2init[gi];
      }
    }
    _Float16 h, l; split2(v, h, l);
    sm[pos * 72 + ci] = h;
    sm[13824 + pos * 72 + ci] = l;
  }
  __syncthreads();

  int lane = tid & 63, w = tid >> 6;
  int kc = w & 1, qh = w >> 1;
  int l16 = lane & 15, quad = lane >> 4;   // l16 = x within row

  f32x4 acch[2][2], accl[2][2];   // [nt][mt]
#pragma unroll
  for (int nt = 0; nt < 2; nt++)
#pragma unroll
    for (int mt = 0; mt < 2; mt++) {
      f32x4 z; z[0] = 0.f; z[1] = 0.f; z[2] = 0.f; z[3] = 0.f;
      accl[nt][mt] = z;
      if (kc == 0) {   // bias enters exactly once (kc=0 partial)
        int cb = cg * 32 + mt * 16 + quad * 4;
        f32x4 bi; bi[0] = b0[cb]; bi[1] = b0[cb + 1]; bi[2] = b0[cb + 2]; bi[3] = b0[cb + 3];
        acch[nt][mt] = bi;
      } else {
        acch[nt][mt] = z;
      }
    }

  for (int tap = 0; tap < 25; tap++) {
    int ky = tap / 5, kx = tap % 5;
    const _Float16* ap  = wA0h + ((tap * 2 + kc) * 128 + cg * 32 + l16) * 32 + quad * 8;
    const _Float16* alp = wA0l + ((tap * 2 + kc) * 128 + cg * 32 + l16) * 32 + quad * 8;
    half8 ah[2], al[2];
#pragma unroll
    for (int mt = 0; mt < 2; mt++) {
      ah[mt] = *(const half8*)(ap + mt * 512);
      al[mt] = *(const half8*)(alp + mt * 512);
    }
#pragma unroll
    for (int nt = 0; nt < 2; nt++) {
      int ly = qh * 2 + nt + ky;           // staged row (y-pad already in slab)
      int ix = l16 + kx - 2;
      bool oob = ((unsigned)ix > 15u);
      int ixc = min(max(ix, 0), 15);
      int pos = ly * 16 + ixc;
      half8 bh = *(const half8*)(sm + pos * 72 + kc * 32 + quad * 8);
      half8 bl = *(const half8*)(sm + 13824 + pos * 72 + kc * 32 + quad * 8);
      if (oob) { bh = hzero(); bl = hzero(); }
#pragma unroll
      for (int mt = 0; mt < 2; mt++) {
        acch[nt][mt] = MFMA_F16(ah[mt], bh, acch[nt][mt]);
        accl[nt][mt] = MFMA_F16(al[mt], bh, accl[nt][mt]);
        accl[nt][mt] = MFMA_F16(ah[mt], bl, accl[nt][mt]);
      }
    }
  }

  // kc-combine via LDS C [co 32][130] (16640 B, reuses sm)
  __syncthreads();
  float* C = (float*)sm;
  if (kc == 0) {
#pragma unroll
    for (int nt = 0; nt < 2; nt++) {
      int pos = (qh * 2 + nt) * 16 + l16;   // 0..127 within half
#pragma unroll
      for (int mt = 0; mt < 2; mt++)
#pragma unroll
        for (int r = 0; r < 4; r++)
          C[(mt * 16 + quad * 4 + r) * 130 + pos] = acch[nt][mt][r] + LO_SCALE * accl[nt][mt][r];
    }
  }
  __syncthreads();
  if (kc == 1) {
#pragma unroll
    for (int nt = 0; nt < 2; nt++) {
      int pos = (qh * 2 + nt) * 16 + l16;
#pragma unroll
      for (int mt = 0; mt < 2; mt++)
#pragma unroll
        for (int r = 0; r < 4; r++) {
          int a = (mt * 16 + quad * 4 + r) * 130 + pos;
          C[a] += acch[nt][mt][r] + LO_SCALE * accl[nt][mt][r];
        }
    }
  }
  __syncthreads();

  // epilogue: 32 co x 32 windows (pooled rows yh*4..yh*4+3)
  for (int it = 0; it < 2; it++) {
    int idx = it * 512 + tid;          // 1024 = 32 co x 32 windows
    int co = idx >> 5, win = idx & 31;
    int phl = win >> 3, pw = win & 7;
    int p0 = phl * 32 + pw * 2;
    float v0 = C[co * 130 + p0];
    float v1 = C[co * 130 + p0 + 1];
    float v2 = C[co * 130 + p0 + 16];
    float v3 = C[co * 130 + p0 + 17];
    float m0 = v0; int id = 0;
    if (v1 > m0) { m0 = v1; id = 1; }
    if (v2 > m0) { m0 = v2; id = 2; }
    if (v3 > m0) { m0 = v3; id = 3; }
    int co_g = cg * 32 + co;
    int ph = yh * 4 + phl;
    int j = co_g * 64 + ph * 8 + pw;
    float a = m0;
#pragma unroll
    for (int k = 0; k < 10; k++) a += s0old[b * 10 + k] * fcw[k * 8192 + j];
    float sv = s1old[b * 8192 + j];
    s1new[b * 8192 + j] = rho_(a);
    _Float16 hh, hl; split2(sv, hh, hl);
    int bu = (b * 256 + ph * 32 + pw * 2) * 128 + co_g;
    _Float16 z = (_Float16)0.f;
    uh[bu]        = (id == 0) ? hh : z;
    ul[bu]        = (id == 0) ? hl : z;
    uh[bu + 128]  = (id == 1) ? hh : z;
    ul[bu + 128]  = (id == 1) ? hl : z;
    uh[bu + 2048] = (id == 2) ? hh : z;
    ul[bu + 2048] = (id == 2) ? hl : z;
    uh[bu + 2176] = (id == 3) ? hh : z;
    ul[bu + 2176] = (id == 3) ? hl : z;
  }
}

// ---------------- K3: convT GEMM (cp-half x o-half x tap-group partial) — unchanged ----------------
__global__ __launch_bounds__(512, 4) void k_convTg(
    const _Float16* __restrict__ uh, const _Float16* __restrict__ ul,
    const _Float16* __restrict__ wA1h, const _Float16* __restrict__ wA1l,
    float* __restrict__ P1) {
  __shared__ __align__(16) _Float16 sm[36864];
  int b = blockIdx.x, tid = threadIdx.x;
  int ks = blockIdx.y & 1;
  int oh = blockIdx.y >> 1;
  int tg = blockIdx.z;

  for (int i = tid; i < 8192; i += 512) {
    int pos = i >> 5, c2 = i & 31;
    int off = b * 32768 + pos * 128 + ks * 64 + c2 * 2;
    *(unsigned*)(sm + pos * 72 + c2 * 2) = *(const unsigned*)(uh + off);
    *(unsigned*)(sm + 18432 + pos * 72 + c2 * 2) = *(const unsigned*)(ul + off);
  }
  __syncthreads();

  int lane = tid & 63, w = tid >> 6;
  int kc = w & 1, qh = w >> 1;
  int l16 = lane & 15, quad = lane >> 4;
  int wy = (l16 >> 1) & 1;
  int x_l = ((l16 >> 2) << 1) + (l16 & 1);

  f32x4 acch[4][2], accl[4][2];
#pragma unroll
  for (int nt = 0; nt < 4; nt++)
#pragma unroll
    for (int mt = 0; mt < 2; mt++) {
      f32x4 z; z[0] = 0.f; z[1] = 0.f; z[2] = 0.f; z[3] = 0.f;
      acch[nt][mt] = z; accl[nt][mt] = z;
    }

  int tap0 = tg * 13, tap1 = tg ? 25 : 13;
  for (int tap = tap0; tap < tap1; tap++) {
    int ky = tap / 5, kx = tap % 5;
    int c = ks * 2 + kc;
    const _Float16* ap  = wA1h + ((tap * 4 + c) * 64 + oh * 32 + l16) * 32 + quad * 8;
    const _Float16* alp = wA1l + ((tap * 4 + c) * 64 + oh * 32 + l16) * 32 + quad * 8;
    half8 ah[2], al[2];
#pragma unroll
    for (int mt = 0; mt < 2; mt++) {
      ah[mt] = *(const half8*)(ap + mt * 512);
      al[mt] = *(const half8*)(alp + mt * 512);
    }
#pragma unroll
    for (int nt = 0; nt < 4; nt++) {
      int y = qh * 4 + (nt >> 1) * 2 + wy;
      int x = (nt & 1) * 8 + x_l;
      int iy = y + 2 - ky, ix = x + 2 - kx;
      bool oob = ((unsigned)iy > 15u) || ((unsigned)ix > 15u);
      int iyc = min(max(iy, 0), 15), ixc = min(max(ix, 0), 15);
      int pos = iyc * 16 + ixc;
      half8 bh = *(const half8*)(sm + pos * 72 + kc * 32 + quad * 8);
      half8 bl = *(const half8*)(sm + 18432 + pos * 72 + kc * 32 + quad * 8);
      if (oob) { bh = hzero(); bl = hzero(); }
#pragma unroll
      for (int mt = 0; mt < 2; mt++) {
        acch[nt][mt] = MFMA_F16(ah[mt], bh, acch[nt][mt]);
        accl[nt][mt] = MFMA_F16(al[mt], bh, accl[nt][mt]);
        accl[nt][mt] = MFMA_F16(ah[mt], bl, accl[nt][mt]);
      }
    }
  }

  __syncthreads();
  float* C = (float*)sm;   // [o 32][260]
  if (kc == 0) {
#pragma unroll
    for (int nt = 0; nt < 4; nt++) {
      int pos = (qh * 4 + (nt >> 1) * 2 + wy) * 16 + (nt & 1) * 8 + x_l;
#pragma unroll
      for (int mt = 0; mt < 2; mt++)
#pragma unroll
        for (int r = 0; r < 4; r++)
          C[(mt * 16 + quad * 4 + r) * 260 + pos] = acch[nt][mt][r] + LO_SCALE * accl[nt][mt][r];
    }
  }
  __syncthreads();
  if (kc == 1) {
#pragma unroll
    for (int nt = 0; nt < 4; nt++) {
      int pos = (qh * 4 + (nt >> 1) * 2 + wy) * 16 + (nt & 1) * 8 + x_l;
#pragma unroll
      for (int mt = 0; mt < 2; mt++)
#pragma unroll
        for (int r = 0; r < 4; r++) {
          int a = (mt * 16 + quad * 4 + r) * 260 + pos;
          C[a] += acch[nt][mt][r] + LO_SCALE * accl[nt][mt][r];
        }
    }
  }
  __syncthreads();

  float* op = P1 + (tg * 2 + ks) * 1048576 + (b * 64 + oh * 32) * 256;
  for (int m = tid; m < 8192; m += 512) {
    int o = m >> 8, pos = m & 255;
    op[o * 256 + pos] = C[o * 260 + pos];
  }
}

// ---------------- K3b: out = rho(p2 + P1[0..3])  (only at t=6 snapshot and t=9 final) ----------------
__global__ __launch_bounds__(256) void k_cTcomb(
    const float* __restrict__ p2, const float* __restrict__ P1,
    float* __restrict__ outv) {
  int i = blockIdx.x * 256 + threadIdx.x;   // over 262144 float4s
  float4 p = ((const float4*)p2)[i];
  float4 a0 = ((const float4*)P1)[i];
  float4 a1 = ((const float4*)(P1 + 1048576))[i];
  float4 a2 = ((const float4*)(P1 + 2097152))[i];
  float4 a3 = ((const float4*)(P1 + 3145728))[i];
  float4 o;
  o.x = rho_(p.x + a0.x + a1.x + a2.x + a3.x);
  o.y = rho_(p.y + a0.y + a1.y + a2.y + a3.y);
  o.z = rho_(p.z + a0.z + a1.z + a2.z + a3.z);
  o.w = rho_(p.w + a0.w + a1.w + a2.w + a3.w);
  ((float4*)outv)[i] = o;
}

// ---------------- K5: s0_new = rho(s1_old_flat @ fc_w^T + fc_b) ----------------
__global__ __launch_bounds__(256) void k_s0fc(
    const float* __restrict__ s1old, const float* __restrict__ fcw,
    const float* __restrict__ fcb, float* __restrict__ s0new) {
  __shared__ float red[10][256];
  int b = blockIdx.x, tid = threadIdx.x;
  float acc[10];
#pragma unroll
  for (int o = 0; o < 10; o++) acc[o] = 0.f;
  const float* sb = s1old + b * 8192;
  for (int i = tid; i < 8192; i += 256) {
    float v = sb[i];
#pragma unroll
    for (int o = 0; o < 10; o++) acc[o] += v * fcw[o * 8192 + i];
  }
#pragma unroll
  for (int o = 0; o < 10; o++) red[o][tid] = acc[o];
  __syncthreads();
  for (int s = 128; s > 0; s >>= 1) {
    if (tid < s) {
#pragma unroll
      for (int o = 0; o < 10; o++) red[o][tid] += red[o][tid + s];
    }
    __syncthreads();
  }
  if (tid < 10) s0new[b * 10 + tid] = rho_(red[tid][0] + fcb[tid]);
}

extern "C" void kernel_launch(void* const* d_in, const int* in_sizes, int n_in,
                              void* d_out, int out_size, void* d_ws, size_t ws_size,
                              hipStream_t stream) {
  const float* data   = (const float*)d_in[0];
  const float* s0init = (const float*)d_in[1];   // zeros
  const float* s1init = (const float*)d_in[2];   // zeros
  const float* s2init = (const float*)d_in[3];   // zeros (t=0 conv0 input)
  const float* conv0w = (const float*)d_in[4];
  const float* conv0b = (const float*)d_in[5];
  const float* conv1w = (const float*)d_in[6];
  const float* conv1b = (const float*)d_in[7];
  const float* fcw    = (const float*)d_in[8];
  const float* fcb    = (const float*)d_in[9];

  // workspace (~35 MB)
  float* p = (float*)d_ws;
  float* s0buf[2] = {p, p + 640};            p += 1280;
  float* s1buf[2] = {p, p + 524288};         p += 1048576;
  float* p2 = p;                             p += 1048576;
  float* P1 = p;                             p += 4194304;   // 4 x 1M convT partials
  _Float16* hq = (_Float16*)p;
  _Float16* uh   = hq;                       hq += 2097152;  // [b][pos 256][cp 128]
  _Float16* ul   = hq;                       hq += 2097152;
  _Float16* wA0h = hq;                       hq += 204800;
  _Float16* wA0l = hq;                       hq += 204800;
  _Float16* wA1h = hq;                       hq += 204800;
  _Float16* wA1l = hq;                       hq += 204800;

  k_wprep<<<800, 256, 0, stream>>>(conv0w, wA0h, wA0l, wA1h, wA1l);
  k_p2<<<dim3(64, 4), 256, 0, stream>>>(data, conv1w, conv1b, p2);

  const float* s0o = s0init;
  const float* s1o = s1init;
  float* outp = (float*)d_out;

  for (int t = 0; t < 10; t++) {
    int nb = t & 1;
    float* s0w = s0buf[nb];
    float* s1w = s1buf[nb];

    // s0_new = rho(fc(s1_old))
    k_s0fc<<<64, 256, 0, stream>>>(s1o, fcw, fcb, s0w);
    // conv0(s2_t) [s2_t = rho(p2+sumP1) fused for t>0] + pool/argmax;
    // s1_new = rho(p1 + fc^T(s0_old)); u = split(unpool(s1_old, idx))
    k_conv0F<<<dim3(64, 4, 2), 512, 0, stream>>>(s2init, p2, P1, (t > 0),
                                                 wA0h, wA0l, conv0b,
                                                 s1o, s0o, fcw, s1w, uh, ul);
    // convT partials (consumed by next step's conv0F staging, or cTcomb at t=6/9)
    k_convTg<<<dim3(64, 4, 2), 512, 0, stream>>>(uh, ul, wA1h, wA1l, P1);

    s0o = s0w; s1o = s1w;

    if (t == 6) {   // PRED_T snapshot (post-update states); s2_7 = rho(p2+sumP1) -> d_out directly
      hipMemcpyAsync(outp + 1573504, s0w, 640 * sizeof(float),    hipMemcpyDeviceToDevice, stream);
      hipMemcpyAsync(outp + 1574144, s1w, 524288 * sizeof(float), hipMemcpyDeviceToDevice, stream);
      k_cTcomb<<<1024, 256, 0, stream>>>(p2, P1, outp + 2098432);
    }
  }

  // final states: s0_10, s1_10 via copies; s2_10 materialized straight into d_out
  hipMemcpyAsync(outp + 0,   s0o, 640 * sizeof(float),    hipMemcpyDeviceToDevice, stream);
  hipMemcpyAsync(outp + 640, s1o, 524288 * sizeof(float), hipMemcpyDeviceToDevice, stream);
  k_cTcomb<<<1024, 256, 0, stream>>>(p2, P1, outp + 524928);
}